// Round 2
// baseline (542.502 us; speedup 1.0000x reference)
//
#include <hip/hip_runtime.h>

#define S_LEN 4096
#define E_DIM 1024
#define NH 8
#define DKD 128

typedef __attribute__((ext_vector_type(8))) short short8;
typedef __attribute__((ext_vector_type(4))) float f32x4;
typedef __attribute__((ext_vector_type(4))) unsigned short ushort4v;

__device__ __forceinline__ unsigned short f32_to_bf16(float f) {
  union { float f; unsigned u; } v; v.f = f;
  unsigned r = v.u + 0x7FFFu + ((v.u >> 16) & 1u);   // RNE
  return (unsigned short)(r >> 16);
}

// async global(16B/lane) -> LDS (wave-uniform base + lane*16)
__device__ __forceinline__ void gld_lds16(const unsigned short* g, unsigned short* l) {
  __builtin_amdgcn_global_load_lds(
      (const __attribute__((address_space(1))) void*)g,
      (__attribute__((address_space(3))) void*)l, 16, 0, 0);
}

// ---------------- fp32 -> bf16 conversion ----------------
__global__ __launch_bounds__(256) void cvt_f32_bf16(const float* __restrict__ src,
                                                    unsigned short* __restrict__ dst,
                                                    int n) {
  int i = (blockIdx.x * 256 + threadIdx.x) * 4;
  if (i >= n) return;
  f32x4 v = *(const f32x4*)(src + i);
  uint2 pk;
  pk.x = (unsigned)f32_to_bf16(v.x) | ((unsigned)f32_to_bf16(v.y) << 16);
  pk.y = (unsigned)f32_to_bf16(v.z) | ((unsigned)f32_to_bf16(v.w) << 16);
  *(uint2*)(dst + i) = pk;
}

// ---------------- Gt[t][s] = mask[s][t] ? bf16(gp[s][t]) : bf16(-1) ----------------
__global__ __launch_bounds__(256) void build_gt(const int* __restrict__ mask,
                                                const float* __restrict__ gp,
                                                unsigned short* __restrict__ Gt) {
  __shared__ unsigned short T[64 * 65];
  const int s0 = blockIdx.x * 64, t0 = blockIdx.y * 64;
  const int tid = threadIdx.x;
  const int r = tid >> 2;            // s-local row
  const int c0 = (tid & 3) * 16;     // t-local col base
  const size_t base = (size_t)(s0 + r) * S_LEN + t0 + c0;
#pragma unroll
  for (int j = 0; j < 16; j += 4) {
    int4 m4 = *(const int4*)(mask + base + j);
    f32x4 g4 = *(const f32x4*)(gp + base + j);
    T[(c0 + j + 0) * 65 + r] = m4.x ? f32_to_bf16(g4.x) : (unsigned short)0xBF80;
    T[(c0 + j + 1) * 65 + r] = m4.y ? f32_to_bf16(g4.y) : (unsigned short)0xBF80;
    T[(c0 + j + 2) * 65 + r] = m4.z ? f32_to_bf16(g4.z) : (unsigned short)0xBF80;
    T[(c0 + j + 3) * 65 + r] = m4.w ? f32_to_bf16(g4.w) : (unsigned short)0xBF80;
  }
  __syncthreads();
  const int tr = tid >> 2;           // t-local row
  const int sc = (tid & 3) * 16;     // s-local col base
  unsigned short tmp[16] __attribute__((aligned(16)));
#pragma unroll
  for (int j = 0; j < 16; ++j) tmp[j] = T[tr * 65 + sc + j];
  *(f32x4*)(Gt + (size_t)(t0 + tr) * S_LEN + s0 + sc) = *(const f32x4*)tmp;
  *(f32x4*)(Gt + (size_t)(t0 + tr) * S_LEN + s0 + sc + 8) = *(const f32x4*)(tmp + 8);
}

// ---------------- m97-style 128x128 bf16 GEMM core: C = A[M,K] * B[N,K]^T ----------------
// LDS tiles [128][32] unpadded, staged via global_load_lds dwordx4.
__device__ __forceinline__ void gemm128_v2(const unsigned short* __restrict__ A,
                                           const unsigned short* __restrict__ B,
                                           int row0, int col0, int K,
                                           unsigned short* As, unsigned short* Bs,
                                           f32x4 acc[4][4]) {
  const int tid = threadIdx.x, lane = tid & 63, wave = tid >> 6;
  const int quad = lane >> 4, l15 = lane & 15;
  const int wm = (wave >> 1) * 64, wn = (wave & 1) * 64;
  const int sr = wave * 32 + (lane >> 2);
  const int sc = (lane & 3) * 8;
  const unsigned short* gA = A + (size_t)(row0 + sr) * K + sc;
  const unsigned short* gB = B + (size_t)(col0 + sr) * K + sc;
  unsigned short* lA = As + wave * 32 * 32;   // wave-uniform
  unsigned short* lB = Bs + wave * 32 * 32;
  for (int k0 = 0; k0 < K; k0 += 32) {
    __syncthreads();
    gld_lds16(gA + k0, lA);
    gld_lds16(gA + k0 + (size_t)16 * K, lA + 16 * 32);
    gld_lds16(gB + k0, lB);
    gld_lds16(gB + k0 + (size_t)16 * K, lB + 16 * 32);
    __syncthreads();
    short8 a[4], b[4];
#pragma unroll
    for (int mt = 0; mt < 4; ++mt)
      a[mt] = *(const short8*)(As + (wm + mt * 16 + l15) * 32 + quad * 8);
#pragma unroll
    for (int nt = 0; nt < 4; ++nt)
      b[nt] = *(const short8*)(Bs + (wn + nt * 16 + l15) * 32 + quad * 8);
#pragma unroll
    for (int mt = 0; mt < 4; ++mt)
#pragma unroll
      for (int nt = 0; nt < 4; ++nt)
        acc[mt][nt] = __builtin_amdgcn_mfma_f32_16x16x32_bf16(a[mt], b[nt], acc[mt][nt], 0, 0, 0);
  }
}

// ---------------- QKV projection ----------------
__global__ __launch_bounds__(256) void proj_qkv(
    const unsigned short* __restrict__ qb, const unsigned short* __restrict__ kb,
    const unsigned short* __restrict__ vb, const unsigned short* __restrict__ Wb,
    const float* __restrict__ bq, const float* __restrict__ bk, const float* __restrict__ bv,
    unsigned short* __restrict__ Qh, unsigned short* __restrict__ Kh,
    unsigned short* __restrict__ Vh, float qscale) {
  __shared__ __attribute__((aligned(16))) unsigned short As[128 * 32];
  __shared__ __attribute__((aligned(16))) unsigned short Bs[128 * 32];
  const int z = blockIdx.z;
  const unsigned short* A = (z == 0) ? qb : (z == 1) ? kb : vb;
  const unsigned short* B = Wb + (size_t)z * E_DIM * E_DIM;
  const float* bias = (z == 0) ? bq : (z == 1) ? bk : bv;
  unsigned short* Out = (z == 0) ? Qh : (z == 1) ? Kh : Vh;
  const float scale = (z == 0) ? qscale : 1.0f;
  const int row0 = blockIdx.y * 128, col0 = blockIdx.x * 128;
  const f32x4 zero4 = {0.f, 0.f, 0.f, 0.f};
  f32x4 acc[4][4];
#pragma unroll
  for (int i = 0; i < 4; ++i)
#pragma unroll
    for (int j = 0; j < 4; ++j) acc[i][j] = zero4;
  gemm128_v2(A, B, row0, col0, E_DIM, As, Bs, acc);
  const int lane = threadIdx.x & 63, wave = threadIdx.x >> 6;
  const int quad = lane >> 4, l15 = lane & 15;
  const int wm = (wave >> 1) * 64, wn = (wave & 1) * 64;
#pragma unroll
  for (int mt = 0; mt < 4; ++mt)
#pragma unroll
    for (int nt = 0; nt < 4; ++nt) {
      int gc = col0 + wn + nt * 16 + l15;
      float bv_ = bias[gc];
#pragma unroll
      for (int r = 0; r < 4; ++r) {
        int gr = row0 + wm + mt * 16 + quad * 4 + r;
        Out[(size_t)gr * E_DIM + gc] = f32_to_bf16((acc[mt][nt][r] + bv_) * scale);
      }
    }
}

// ---------------- output projection + bias + residual ----------------
__global__ __launch_bounds__(256) void out_proj(
    const unsigned short* __restrict__ Zb, const unsigned short* __restrict__ Wob,
    const float* __restrict__ bo, const float* __restrict__ resid,
    float* __restrict__ Y) {
  __shared__ __attribute__((aligned(16))) unsigned short As[128 * 32];
  __shared__ __attribute__((aligned(16))) unsigned short Bs[128 * 32];
  const int row0 = blockIdx.y * 128, col0 = blockIdx.x * 128;
  const f32x4 zero4 = {0.f, 0.f, 0.f, 0.f};
  f32x4 acc[4][4];
#pragma unroll
  for (int i = 0; i < 4; ++i)
#pragma unroll
    for (int j = 0; j < 4; ++j) acc[i][j] = zero4;
  gemm128_v2(Zb, Wob, row0, col0, E_DIM, As, Bs, acc);
  const int lane = threadIdx.x & 63, wave = threadIdx.x >> 6;
  const int quad = lane >> 4, l15 = lane & 15;
  const int wm = (wave >> 1) * 64, wn = (wave & 1) * 64;
#pragma unroll
  for (int mt = 0; mt < 4; ++mt)
#pragma unroll
    for (int nt = 0; nt < 4; ++nt) {
      int gc = col0 + wn + nt * 16 + l15;
      float bv_ = bo[gc];
#pragma unroll
      for (int r = 0; r < 4; ++r) {
        int gr = row0 + wm + mt * 16 + quad * 4 + r;
        Y[(size_t)gr * E_DIM + gc] = acc[mt][nt][r] + bv_ + resid[(size_t)gr * E_DIM + gc];
      }
    }
}

// ---------------- V transpose: Vh[S, H*DK] -> Vt[H][DK][S] ----------------
__global__ __launch_bounds__(256) void transpose_v(const unsigned short* __restrict__ Vh,
                                                   unsigned short* __restrict__ Vt) {
  __shared__ __attribute__((aligned(16))) unsigned short T[64 * 72];
  const int t0 = blockIdx.x * 64, d0 = blockIdx.y * 64, h = blockIdx.z;
  const int tid = threadIdx.x;
#pragma unroll
  for (int i = 0; i < 2; ++i) {
    int c = tid + i * 256;
    int r = c >> 3, cc = c & 7;
    *(f32x4*)(T + r * 72 + cc * 8) =
        *(const f32x4*)(Vh + (size_t)(t0 + r) * E_DIM + h * DKD + d0 + cc * 8);
  }
  __syncthreads();
#pragma unroll
  for (int i = 0; i < 2; ++i) {
    int c = tid + i * 256;
    int r = c >> 3, cc = c & 7;
    unsigned short tmp[8] __attribute__((aligned(16)));
#pragma unroll
    for (int j = 0; j < 8; ++j) tmp[j] = T[(cc * 8 + j) * 72 + r];
    *(f32x4*)(Vt + (size_t)(h * DKD + d0 + r) * S_LEN + t0 + cc * 8) = *(const f32x4*)tmp;
  }
}

// ---------------- flash attention, Gt-fused mask/group_prob ----------------
// grid (H, S/64); 4 waves; wave w owns Q rows w*16..+16. K double-buffered (early
// issue overlaps staging with compute), V single-buffered, P LDS per-wave (no barrier).
__global__ __launch_bounds__(256) void attn_fwd(
    const unsigned short* __restrict__ Qh, const unsigned short* __restrict__ Kh,
    const unsigned short* __restrict__ Vt, const unsigned short* __restrict__ Gt,
    unsigned short* __restrict__ Z) {
  __shared__ __attribute__((aligned(16))) unsigned short Ks[2][4][64][32];
  __shared__ __attribute__((aligned(16))) unsigned short Vs[2][128][32];
  __shared__ __attribute__((aligned(16))) unsigned short Ps[4][16][80];
  const int h = blockIdx.x;
  const int q0 = blockIdx.y * 64;
  const int tid = threadIdx.x;
  const int wave = tid >> 6, lane = tid & 63;
  const int quad = lane >> 4, l15 = lane & 15;
  const int srow16 = lane >> 2;
  const int scol = (lane & 3) * 8;
  const int hv = wave & 1, db = wave >> 1;

  const unsigned short* gK = Kh + (size_t)srow16 * E_DIM + h * DKD + wave * 32 + scol;
  const unsigned short* gV = Vt + (size_t)(h * DKD + db * 64 + srow16) * S_LEN + hv * 32 + scol;

  // Q fragments in registers
  const unsigned short* qp = Qh + (size_t)(q0 + wave * 16 + l15) * E_DIM + h * DKD;
  short8 aq[4];
#pragma unroll
  for (int kk = 0; kk < 4; ++kk) aq[kk] = *(const short8*)(qp + kk * 32 + quad * 8);

  float m_i[4], l_i[4];
#pragma unroll
  for (int r = 0; r < 4; ++r) { m_i[r] = -1e30f; l_i[r] = 0.0f; }
  const f32x4 zero4 = {0.f, 0.f, 0.f, 0.f};
  f32x4 o[8];
#pragma unroll
  for (int d = 0; d < 8; ++d) o[d] = zero4;

  // prologue staging of tile 0
#pragma unroll
  for (int c = 0; c < 4; ++c) {
    gld_lds16(gK + (size_t)(c * 16) * E_DIM, &Ks[0][wave][c * 16][0]);
    gld_lds16(gV + (size_t)(c * 16) * S_LEN, &Vs[hv][db * 64 + c * 16][0]);
  }
  __syncthreads();

  for (int it = 0; it < S_LEN / 64; ++it) {
    const int t0 = it * 64;
    const int cur = it & 1;
    // early-issue K(t+1) into the other buffer; drains at end-of-compute barrier
    if (it + 1 < S_LEN / 64) {
#pragma unroll
      for (int c = 0; c < 4; ++c)
        gld_lds16(gK + (size_t)(t0 + 64 + c * 16) * E_DIM, &Ks[1 - cur][wave][c * 16][0]);
    }
    // S = Q K^T
    f32x4 sA[4];
#pragma unroll
    for (int nt = 0; nt < 4; ++nt) {
      sA[nt] = zero4;
#pragma unroll
      for (int kk = 0; kk < 4; ++kk) {
        short8 bK = *(const short8*)&Ks[cur][kk][nt * 16 + l15][quad * 8];
        sA[nt] = __builtin_amdgcn_mfma_f32_16x16x32_bf16(aq[kk], bK, sA[nt], 0, 0, 0);
      }
    }
    // Gt loads (8B vector: 4 consecutive s) + mask select
    const int srow = q0 + wave * 16 + quad * 4;
    float gmf[4][4], p[4][4];
#pragma unroll
    for (int nt = 0; nt < 4; ++nt) {
      int tg = t0 + nt * 16 + l15;
      ushort4v g4 = *(const ushort4v*)(Gt + (size_t)tg * S_LEN + srow);
#pragma unroll
      for (int r = 0; r < 4; ++r) {
        union { unsigned u; float f; } cv; cv.u = ((unsigned)g4[r]) << 16;
        gmf[nt][r] = cv.f;
        p[nt][r] = (cv.f < 0.0f) ? -1e9f : sA[nt][r];   // masked -> -1e9, exp -> exactly 0
      }
    }
    // online softmax (rows in 16-lane groups)
    float alpha[4];
    bool need = false;
#pragma unroll
    for (int r = 0; r < 4; ++r) {
      float vm = fmaxf(fmaxf(p[0][r], p[1][r]), fmaxf(p[2][r], p[3][r]));
#pragma unroll
      for (int off = 1; off < 16; off <<= 1) vm = fmaxf(vm, __shfl_xor(vm, off, 64));
      float mnew = fmaxf(m_i[r], vm);
      alpha[r] = __expf(m_i[r] - mnew);
      need |= (vm > m_i[r]);
      m_i[r] = mnew;
      float ps = 0.0f;
#pragma unroll
      for (int nt = 0; nt < 4; ++nt) {
        float pv = __expf(p[nt][r] - mnew);
        p[nt][r] = pv;
        ps += pv;
      }
#pragma unroll
      for (int off = 1; off < 16; off <<= 1) ps += __shfl_xor(ps, off, 64);
      l_i[r] = l_i[r] * alpha[r] + ps;
    }
    if (__any((int)need)) {
#pragma unroll
      for (int dt = 0; dt < 8; ++dt)
#pragma unroll
        for (int r = 0; r < 4; ++r) o[dt][r] *= alpha[r];
    }
    // P * gm -> per-wave LDS (C-layout -> A-layout); same-wave, no barrier needed
#pragma unroll
    for (int nt = 0; nt < 4; ++nt)
#pragma unroll
      for (int r = 0; r < 4; ++r)
        Ps[wave][quad * 4 + r][nt * 16 + l15] = f32_to_bf16(p[nt][r] * gmf[nt][r]);
    short8 ap0 = *(const short8*)&Ps[wave][l15][quad * 8];
    short8 ap1 = *(const short8*)&Ps[wave][l15][32 + quad * 8];
    // O += P V
#pragma unroll
    for (int dt = 0; dt < 8; ++dt) {
      short8 b0 = *(const short8*)&Vs[0][dt * 16 + l15][quad * 8];
      short8 b1 = *(const short8*)&Vs[1][dt * 16 + l15][quad * 8];
      o[dt] = __builtin_amdgcn_mfma_f32_16x16x32_bf16(ap0, b0, o[dt], 0, 0, 0);
      o[dt] = __builtin_amdgcn_mfma_f32_16x16x32_bf16(ap1, b1, o[dt], 0, 0, 0);
    }
    __syncthreads();   // all waves done with Vs/Ks[cur]; drains early-issued K(t+1)
    if (it + 1 < S_LEN / 64) {
#pragma unroll
      for (int c = 0; c < 4; ++c)
        gld_lds16(gV + (size_t)(c * 16) * S_LEN + t0 + 64, &Vs[hv][db * 64 + c * 16][0]);
      __syncthreads();
    }
  }

#pragma unroll
  for (int dt = 0; dt < 8; ++dt)
#pragma unroll
    for (int r = 0; r < 4; ++r) {
      int gr = q0 + wave * 16 + quad * 4 + r;
      int gc = h * DKD + dt * 16 + l15;
      Z[(size_t)gr * E_DIM + gc] = f32_to_bf16(o[dt][r] / l_i[r]);
    }
}

// ---------------- LayerNorm ----------------
__global__ __launch_bounds__(256) void ln_fwd(const float* __restrict__ Y,
                                              const float* __restrict__ g,
                                              const float* __restrict__ b,
                                              float* __restrict__ out) {
  const int row = blockIdx.x;
  const int tid = threadIdx.x;
  const float* y = Y + (size_t)row * E_DIM;
  f32x4 v = *(const f32x4*)(y + tid * 4);
  float s = v.x + v.y + v.z + v.w;
  float s2 = v.x * v.x + v.y * v.y + v.z * v.z + v.w * v.w;
#pragma unroll
  for (int off = 32; off > 0; off >>= 1) {
    s += __shfl_down(s, off, 64);
    s2 += __shfl_down(s2, off, 64);
  }
  __shared__ float red[8];
  __shared__ float mu_s, rs_s;
  const int wave = tid >> 6, lane = tid & 63;
  if (lane == 0) { red[wave] = s; red[4 + wave] = s2; }
  __syncthreads();
  if (tid == 0) {
    float ts = red[0] + red[1] + red[2] + red[3];
    float ts2 = red[4] + red[5] + red[6] + red[7];
    float mu = ts * (1.0f / E_DIM);
    float var = ts2 * (1.0f / E_DIM) - mu * mu;
    mu_s = mu;
    rs_s = rsqrtf(var + 1e-5f);
  }
  __syncthreads();
  const float mu = mu_s, rs = rs_s;
  f32x4 gg = *(const f32x4*)(g + tid * 4);
  f32x4 bb = *(const f32x4*)(b + tid * 4);
  f32x4 ov;
  ov.x = (v.x - mu) * rs * gg.x + bb.x;
  ov.y = (v.y - mu) * rs * gg.y + bb.y;
  ov.z = (v.z - mu) * rs * gg.z + bb.z;
  ov.w = (v.w - mu) * rs * gg.w + bb.w;
  *(f32x4*)(out + (size_t)row * E_DIM + tid * 4) = ov;
}

extern "C" void kernel_launch(void* const* d_in, const int* in_sizes, int n_in,
                              void* d_out, int out_size, void* d_ws, size_t ws_size,
                              hipStream_t stream) {
  const float* q   = (const float*)d_in[0];
  const float* k   = (const float*)d_in[1];
  const float* v   = (const float*)d_in[2];
  const int*  mask = (const int*)d_in[3];
  const float* gp  = (const float*)d_in[4];
  const float* Wq  = (const float*)d_in[5];
  const float* bq  = (const float*)d_in[6];
  const float* Wk  = (const float*)d_in[7];
  const float* bk  = (const float*)d_in[8];
  const float* Wv  = (const float*)d_in[9];
  const float* bv  = (const float*)d_in[10];
  const float* Wo  = (const float*)d_in[11];
  const float* bo  = (const float*)d_in[12];
  const float* lng = (const float*)d_in[13];
  const float* lnb = (const float*)d_in[14];

  char* ws = (char*)d_ws;
  const size_t MB = 1024 * 1024;
  // layout (88 MB peak, lifetimes disjoint where overlapped):
  unsigned short* WB = (unsigned short*)(ws + 0);        // Wq,Wk,Wv bf16 [0,6)
  unsigned short* WOB = (unsigned short*)(ws + 6 * MB);  // Wo bf16 [6,8)
  unsigned short* QB = (unsigned short*)(ws + 8 * MB);   // [8,16)  dead after proj
  unsigned short* KB = (unsigned short*)(ws + 16 * MB);  // [16,24) dead after proj
  unsigned short* VB = (unsigned short*)(ws + 24 * MB);  // [24,32) dead after proj
  unsigned short* GT = (unsigned short*)(ws + 8 * MB);   // [8,40)  built after proj
  unsigned short* KH = (unsigned short*)(ws + 40 * MB);  // [40,48)
  unsigned short* VH = (unsigned short*)(ws + 48 * MB);  // [48,56)
  unsigned short* VT = (unsigned short*)(ws + 56 * MB);  // [56,64)
  unsigned short* ZB = (unsigned short*)(ws + 64 * MB);  // [64,72)
  unsigned short* QH = (unsigned short*)(ws + 72 * MB);  // [72,80) dead after attn
  float* YF = (float*)(ws + 72 * MB);                    // [72,88) used after attn

  const int nQKV = S_LEN * E_DIM;
  const int nW = E_DIM * E_DIM;
  cvt_f32_bf16<<<nQKV / 1024, 256, 0, stream>>>(q, QB, nQKV);
  cvt_f32_bf16<<<nQKV / 1024, 256, 0, stream>>>(k, KB, nQKV);
  cvt_f32_bf16<<<nQKV / 1024, 256, 0, stream>>>(v, VB, nQKV);
  cvt_f32_bf16<<<nW / 1024, 256, 0, stream>>>(Wq, WB + 0 * (size_t)nW, nW);
  cvt_f32_bf16<<<nW / 1024, 256, 0, stream>>>(Wk, WB + 1 * (size_t)nW, nW);
  cvt_f32_bf16<<<nW / 1024, 256, 0, stream>>>(Wv, WB + 2 * (size_t)nW, nW);
  cvt_f32_bf16<<<nW / 1024, 256, 0, stream>>>(Wo, WOB, nW);

  proj_qkv<<<dim3(8, 32, 3), 256, 0, stream>>>(QB, KB, VB, WB, bq, bk, bv,
                                               QH, KH, VH, 0.08838834764831845f);
  build_gt<<<dim3(64, 64), 256, 0, stream>>>(mask, gp, GT);   // overwrites QB/KB/VB
  transpose_v<<<dim3(64, 2, 8), 256, 0, stream>>>(VH, VT);
  attn_fwd<<<dim3(8, 64), 256, 0, stream>>>(QH, KH, VT, GT, ZB);
  out_proj<<<dim3(8, 32), 256, 0, stream>>>(ZB, WOB, bo, q, YF);
  ln_fwd<<<S_LEN, 256, 0, stream>>>(YF, lng, lnb, (float*)d_out);
}

// Round 3
// 503.290 us; speedup vs baseline: 1.0779x; 1.0779x over previous
//
#include <hip/hip_runtime.h>

#define S_LEN 4096
#define E_DIM 1024
#define NH 8
#define DKD 128

typedef __attribute__((ext_vector_type(8))) short short8;
typedef __attribute__((ext_vector_type(4))) float f32x4;
typedef __attribute__((ext_vector_type(4))) unsigned short ushort4v;

#if __has_builtin(__builtin_amdgcn_exp2f)
#define EXP2F(x) __builtin_amdgcn_exp2f(x)
#else
#define EXP2F(x) exp2f(x)
#endif

// log2(e)/sqrt(128): folded into Q so QK^T scores are already in exp2 domain
#define QSCALE 0.12753819953924682f

__device__ __forceinline__ unsigned short f32_to_bf16(float f) {
  union { float f; unsigned u; } v; v.f = f;
  unsigned r = v.u + 0x7FFFu + ((v.u >> 16) & 1u);   // RNE
  return (unsigned short)(r >> 16);
}

__device__ __forceinline__ void gld_lds16(const unsigned short* g, unsigned short* l) {
  __builtin_amdgcn_global_load_lds(
      (const __attribute__((address_space(1))) void*)g,
      (__attribute__((address_space(3))) void*)l, 16, 0, 0);
}

// ---------------- fused fp32 -> bf16 conversion, 3 same-size tensors ----------------
__global__ __launch_bounds__(256) void cvt3(const float* __restrict__ a,
                                            const float* __restrict__ b,
                                            const float* __restrict__ c,
                                            unsigned short* __restrict__ dst, int n) {
  const float* src = (blockIdx.y == 0) ? a : (blockIdx.y == 1) ? b : c;
  unsigned short* d = dst + (size_t)blockIdx.y * n;
  int i = (blockIdx.x * 256 + threadIdx.x) * 4;
  if (i >= n) return;
  f32x4 v = *(const f32x4*)(src + i);
  uint2 pk;
  pk.x = (unsigned)f32_to_bf16(v.x) | ((unsigned)f32_to_bf16(v.y) << 16);
  pk.y = (unsigned)f32_to_bf16(v.z) | ((unsigned)f32_to_bf16(v.w) << 16);
  *(uint2*)(d + i) = pk;
}

__global__ __launch_bounds__(256) void cvt4(const float* __restrict__ a,
                                            const float* __restrict__ b,
                                            const float* __restrict__ c,
                                            const float* __restrict__ e,
                                            unsigned short* __restrict__ dst, int n) {
  const float* src = (blockIdx.y == 0) ? a : (blockIdx.y == 1) ? b
                   : (blockIdx.y == 2) ? c : e;
  unsigned short* d = dst + (size_t)blockIdx.y * n;
  int i = (blockIdx.x * 256 + threadIdx.x) * 4;
  if (i >= n) return;
  f32x4 v = *(const f32x4*)(src + i);
  uint2 pk;
  pk.x = (unsigned)f32_to_bf16(v.x) | ((unsigned)f32_to_bf16(v.y) << 16);
  pk.y = (unsigned)f32_to_bf16(v.z) | ((unsigned)f32_to_bf16(v.w) << 16);
  *(uint2*)(d + i) = pk;
}

// ---------------- Gt[t][s] = mask[s][t] ? bf16(gp[s][t]) : bf16(-1) ----------------
__global__ __launch_bounds__(256) void build_gt(const int* __restrict__ mask,
                                                const float* __restrict__ gp,
                                                unsigned short* __restrict__ Gt) {
  __shared__ unsigned short T[64 * 65];
  const int s0 = blockIdx.x * 64, t0 = blockIdx.y * 64;
  const int tid = threadIdx.x;
  const int r = tid >> 2;
  const int c0 = (tid & 3) * 16;
  const size_t base = (size_t)(s0 + r) * S_LEN + t0 + c0;
#pragma unroll
  for (int j = 0; j < 16; j += 4) {
    int4 m4 = *(const int4*)(mask + base + j);
    f32x4 g4 = *(const f32x4*)(gp + base + j);
    T[(c0 + j + 0) * 65 + r] = m4.x ? f32_to_bf16(g4.x) : (unsigned short)0xBF80;
    T[(c0 + j + 1) * 65 + r] = m4.y ? f32_to_bf16(g4.y) : (unsigned short)0xBF80;
    T[(c0 + j + 2) * 65 + r] = m4.z ? f32_to_bf16(g4.z) : (unsigned short)0xBF80;
    T[(c0 + j + 3) * 65 + r] = m4.w ? f32_to_bf16(g4.w) : (unsigned short)0xBF80;
  }
  __syncthreads();
  const int tr = tid >> 2;
  const int sc = (tid & 3) * 16;
  unsigned short tmp[16] __attribute__((aligned(16)));
#pragma unroll
  for (int j = 0; j < 16; ++j) tmp[j] = T[tr * 65 + sc + j];
  *(f32x4*)(Gt + (size_t)(t0 + tr) * S_LEN + s0 + sc) = *(const f32x4*)tmp;
  *(f32x4*)(Gt + (size_t)(t0 + tr) * S_LEN + s0 + sc + 8) = *(const f32x4*)(tmp + 8);
}

// ---------------- swizzled 128x128 bf16 GEMM core: C = A[M,K] * B[N,K]^T ----------------
// LDS [row][32] unpadded (global_load_lds-compatible); 8-chunk XOR swizzle on the
// GLOBAL source column makes frag ds_read_b128 2-way (free) instead of 8-way.
__device__ __forceinline__ void gemm128_v3(const unsigned short* __restrict__ A,
                                           const unsigned short* __restrict__ B,
                                           int row0, int col0, int K,
                                           unsigned short* As, unsigned short* Bs,
                                           f32x4 acc[4][4]) {
  const int tid = threadIdx.x, lane = tid & 63, wave = tid >> 6;
  const int quad = lane >> 4, l15 = lane & 15;
  const int wm = (wave >> 1) * 64, wn = (wave & 1) * 64;
  const int sr = wave * 32 + (lane >> 2);
  const int srow = lane >> 2;
  const int ssw = (((lane & 3) ^ ((srow ^ (srow >> 2)) & 3)) * 8);  // staging swizzle
  const int kswz = ((quad ^ ((l15 ^ (l15 >> 2)) & 3)) * 8);         // frag-read swizzle
  const unsigned short* gA = A + (size_t)(row0 + sr) * K + ssw;
  const unsigned short* gB = B + (size_t)(col0 + sr) * K + ssw;
  unsigned short* lA = As + wave * 32 * 32;
  unsigned short* lB = Bs + wave * 32 * 32;
  for (int k0 = 0; k0 < K; k0 += 32) {
    __syncthreads();
    gld_lds16(gA + k0, lA);
    gld_lds16(gA + k0 + (size_t)16 * K, lA + 16 * 32);
    gld_lds16(gB + k0, lB);
    gld_lds16(gB + k0 + (size_t)16 * K, lB + 16 * 32);
    __syncthreads();
    short8 a[4], b[4];
#pragma unroll
    for (int mt = 0; mt < 4; ++mt)
      a[mt] = *(const short8*)(As + (wm + mt * 16 + l15) * 32 + kswz);
#pragma unroll
    for (int nt = 0; nt < 4; ++nt)
      b[nt] = *(const short8*)(Bs + (wn + nt * 16 + l15) * 32 + kswz);
#pragma unroll
    for (int mt = 0; mt < 4; ++mt)
#pragma unroll
      for (int nt = 0; nt < 4; ++nt)
        acc[mt][nt] = __builtin_amdgcn_mfma_f32_16x16x32_bf16(a[mt], b[nt], acc[mt][nt], 0, 0, 0);
  }
}

// ---------------- QKV projection ----------------
// z=0/1 (Q,K): C[e][s] = W x^T -> packed 8B stores of 4 consecutive e at fixed s.
// z=2  (V):    C[s][e] = x W^T -> packed 8B stores of 4 consecutive s -> writes V^T directly.
__global__ __launch_bounds__(256) void proj_qkv(
    const unsigned short* __restrict__ xb, const unsigned short* __restrict__ Wb,
    const float* __restrict__ bq, const float* __restrict__ bk, const float* __restrict__ bv,
    unsigned short* __restrict__ Qh, unsigned short* __restrict__ Kh,
    unsigned short* __restrict__ Vt) {
  __shared__ __attribute__((aligned(16))) unsigned short As[128 * 32];
  __shared__ __attribute__((aligned(16))) unsigned short Bs[128 * 32];
  const int z = blockIdx.z;
  const unsigned short* X = xb + (size_t)z * S_LEN * E_DIM;
  const unsigned short* W = Wb + (size_t)z * E_DIM * E_DIM;
  const float* bias = (z == 0) ? bq : (z == 1) ? bk : bv;
  const f32x4 zero4 = {0.f, 0.f, 0.f, 0.f};
  f32x4 acc[4][4];
#pragma unroll
  for (int i = 0; i < 4; ++i)
#pragma unroll
    for (int j = 0; j < 4; ++j) acc[i][j] = zero4;
  const int lane = threadIdx.x & 63, wave = threadIdx.x >> 6;
  const int quad = lane >> 4, l15 = lane & 15;
  const int wm = (wave >> 1) * 64, wn = (wave & 1) * 64;
  if (z < 2) {
    const int row0 = blockIdx.y * 128;   // e
    const int col0 = blockIdx.x * 128;   // s
    gemm128_v3(W, X, row0, col0, E_DIM, As, Bs, acc);
    unsigned short* Out = (z == 0) ? Qh : Kh;
    const float scale = (z == 0) ? QSCALE : 1.0f;
#pragma unroll
    for (int mt = 0; mt < 4; ++mt) {
      int ge = row0 + wm + mt * 16 + quad * 4;
      f32x4 b4 = *(const f32x4*)(bias + ge);
#pragma unroll
      for (int nt = 0; nt < 4; ++nt) {
        int gs = col0 + wn + nt * 16 + l15;
        ushort4v pk;
#pragma unroll
        for (int r = 0; r < 4; ++r) pk[r] = f32_to_bf16((acc[mt][nt][r] + b4[r]) * scale);
        *(ushort4v*)(Out + (size_t)gs * E_DIM + ge) = pk;
      }
    }
  } else {
    const int row0 = blockIdx.x * 128;   // s
    const int col0 = blockIdx.y * 128;   // e
    gemm128_v3(X, W, row0, col0, E_DIM, As, Bs, acc);
#pragma unroll
    for (int nt = 0; nt < 4; ++nt) {
      int ge = col0 + wn + nt * 16 + l15;
      float bv_ = bias[ge];
#pragma unroll
      for (int mt = 0; mt < 4; ++mt) {
        int gs = row0 + wm + mt * 16 + quad * 4;
        ushort4v pk;
#pragma unroll
        for (int r = 0; r < 4; ++r) pk[r] = f32_to_bf16(acc[mt][nt][r] + bv_);
        *(ushort4v*)(Vt + (size_t)ge * S_LEN + gs) = pk;   // V^T [e][s]
      }
    }
  }
}

// ---------------- output projection + bias + residual: C[e][s], f32x4 stores ----------------
__global__ __launch_bounds__(256) void out_proj(
    const unsigned short* __restrict__ Zb, const unsigned short* __restrict__ Wob,
    const float* __restrict__ bo, const float* __restrict__ resid,
    float* __restrict__ Y) {
  __shared__ __attribute__((aligned(16))) unsigned short As[128 * 32];
  __shared__ __attribute__((aligned(16))) unsigned short Bs[128 * 32];
  const int row0 = blockIdx.y * 128;  // e
  const int col0 = blockIdx.x * 128;  // s
  const f32x4 zero4 = {0.f, 0.f, 0.f, 0.f};
  f32x4 acc[4][4];
#pragma unroll
  for (int i = 0; i < 4; ++i)
#pragma unroll
    for (int j = 0; j < 4; ++j) acc[i][j] = zero4;
  gemm128_v3(Wob, Zb, row0, col0, E_DIM, As, Bs, acc);
  const int lane = threadIdx.x & 63, wave = threadIdx.x >> 6;
  const int quad = lane >> 4, l15 = lane & 15;
  const int wm = (wave >> 1) * 64, wn = (wave & 1) * 64;
#pragma unroll
  for (int mt = 0; mt < 4; ++mt) {
    int ge = row0 + wm + mt * 16 + quad * 4;
    f32x4 b4 = *(const f32x4*)(bo + ge);
#pragma unroll
    for (int nt = 0; nt < 4; ++nt) {
      int gs = col0 + wn + nt * 16 + l15;
      f32x4 r4 = *(const f32x4*)(resid + (size_t)gs * E_DIM + ge);
      f32x4 ov = acc[mt][nt] + b4 + r4;
      *(f32x4*)(Y + (size_t)gs * E_DIM + ge) = ov;
    }
  }
}

// ---------------- flash attention: 128 q-rows/block, fixed-base softmax ----------------
// grid (32 q-tiles, 8 heads) = 256 blocks = 1/CU. Wave owns 32 q-rows (2 MFMA sets).
// K,V double-buffered (swizzled LDS), single barrier/tile, no in-loop cross-lane ops.
__global__ __launch_bounds__(256, 1) void attn_fwd(
    const unsigned short* __restrict__ Qh, const unsigned short* __restrict__ Kh,
    const unsigned short* __restrict__ Vt, const unsigned short* __restrict__ Gt,
    unsigned short* __restrict__ Z) {
  __shared__ __attribute__((aligned(16))) unsigned short Ks[2][4][64][32];
  __shared__ __attribute__((aligned(16))) unsigned short Vs[2][2][128][32];
  __shared__ __attribute__((aligned(16))) unsigned short Ps[4][32 * 68];
  const int qt = blockIdx.x, h = blockIdx.y;
  const int q0 = qt * 128;
  const int tid = threadIdx.x;
  const int wave = tid >> 6, lane = tid & 63;
  const int quad = lane >> 4, l15 = lane & 15;
  const int srow = lane >> 2;
  const int ssw = (((lane & 3) ^ ((srow ^ (srow >> 2)) & 3)) * 8);
  const int kswz = ((quad ^ ((l15 ^ (l15 >> 2)) & 3)) * 8);

  const unsigned short* gK = Kh + (size_t)srow * E_DIM + h * DKD + wave * 32 + ssw;
  const unsigned short* gV = Vt + (size_t)(h * DKD + (wave >> 1) * 64 + srow) * S_LEN
                             + (wave & 1) * 32 + ssw;

  // Q fragments in registers (Qh is [e][s]-major? no: Qh[s][e], K-contiguous e) --
  // Qh stored as [s][e] with e contiguous: row s, cols h*128..+128.
  short8 aq[2][4];
#pragma unroll
  for (int s = 0; s < 2; ++s) {
    const unsigned short* qp =
        Qh + (size_t)(q0 + wave * 32 + s * 16 + l15) * E_DIM + h * DKD;
#pragma unroll
    for (int kk = 0; kk < 4; ++kk)
      aq[s][kk] = *(const short8*)(qp + kk * 32 + quad * 8);
  }

  float l_i[2][4];
#pragma unroll
  for (int s = 0; s < 2; ++s)
#pragma unroll
    for (int r = 0; r < 4; ++r) l_i[s][r] = 0.0f;
  const f32x4 zero4 = {0.f, 0.f, 0.f, 0.f};
  f32x4 o[2][8];
#pragma unroll
  for (int s = 0; s < 2; ++s)
#pragma unroll
    for (int d = 0; d < 8; ++d) o[s][d] = zero4;

  // prologue: stage tile 0 into buffer 0
#pragma unroll
  for (int c = 0; c < 4; ++c) {
    gld_lds16(gK + (size_t)(c * 16) * E_DIM, &Ks[0][wave][c * 16][0]);
    gld_lds16(gV + (size_t)(c * 16) * S_LEN, &Vs[0][wave & 1][(wave >> 1) * 64 + c * 16][0]);
  }
  __syncthreads();

  const int srow0 = q0 + wave * 32 + quad * 4;

  for (int it = 0; it < S_LEN / 64; ++it) {
    const int t0 = it * 64;
    const int cur = it & 1, nxt = 1 - cur;

    // Gt loads FIRST (so their vmcnt wait doesn't drain the prefetch below)
    ushort4v g4[2][4];
#pragma unroll
    for (int s = 0; s < 2; ++s)
#pragma unroll
      for (int nt = 0; nt < 4; ++nt) {
        int tg = t0 + nt * 16 + l15;
        g4[s][nt] = *(const ushort4v*)(Gt + (size_t)tg * S_LEN + srow0 + s * 16);
      }

    // prefetch next K/V tile
    if (it + 1 < S_LEN / 64) {
      const int t0n = t0 + 64;
#pragma unroll
      for (int c = 0; c < 4; ++c) {
        gld_lds16(gK + (size_t)(t0n + c * 16) * E_DIM, &Ks[nxt][wave][c * 16][0]);
        gld_lds16(gV + (size_t)(c * 16) * S_LEN + t0n,
                  &Vs[nxt][wave & 1][(wave >> 1) * 64 + c * 16][0]);
      }
    }

    // S' = Q K^T (already in exp2 domain via QSCALE), both row-sets share bK reads
    f32x4 sA[2][4];
#pragma unroll
    for (int nt = 0; nt < 4; ++nt) { sA[0][nt] = zero4; sA[1][nt] = zero4; }
#pragma unroll
    for (int nt = 0; nt < 4; ++nt)
#pragma unroll
      for (int kk = 0; kk < 4; ++kk) {
        short8 bK = *(const short8*)&Ks[cur][kk][nt * 16 + l15][kswz];
        sA[0][nt] = __builtin_amdgcn_mfma_f32_16x16x32_bf16(aq[0][kk], bK, sA[0][nt], 0, 0, 0);
        sA[1][nt] = __builtin_amdgcn_mfma_f32_16x16x32_bf16(aq[1][kk], bK, sA[1][nt], 0, 0, 0);
      }

    // fixed-base softmax: p = exp2(s'), masked -> 0; l accumulates per-lane
#pragma unroll
    for (int s = 0; s < 2; ++s)
#pragma unroll
      for (int nt = 0; nt < 4; ++nt)
#pragma unroll
        for (int r = 0; r < 4; ++r) {
          union { unsigned u; float f; } cv; cv.u = ((unsigned)g4[s][nt][r]) << 16;
          float x = (cv.f < 0.0f) ? -1e9f : sA[s][nt][r];
          float e = EXP2F(x);
          l_i[s][r] += e;
          union { float f; unsigned u; } pb; pb.f = e * cv.f;
          Ps[wave][(s * 16 + quad * 4 + r) * 68 + nt * 16 + l15] =
              (unsigned short)((pb.u + 0x8000u) >> 16);
        }

    // O += P V (V-frag reads shared by both row-sets)
    short8 ap00 = *(const short8*)&Ps[wave][l15 * 68 + quad * 8];
    short8 ap01 = *(const short8*)&Ps[wave][l15 * 68 + 32 + quad * 8];
    short8 ap10 = *(const short8*)&Ps[wave][(16 + l15) * 68 + quad * 8];
    short8 ap11 = *(const short8*)&Ps[wave][(16 + l15) * 68 + 32 + quad * 8];
#pragma unroll
    for (int dt = 0; dt < 8; ++dt) {
      short8 b0 = *(const short8*)&Vs[cur][0][dt * 16 + l15][kswz];
      short8 b1 = *(const short8*)&Vs[cur][1][dt * 16 + l15][kswz];
      o[0][dt] = __builtin_amdgcn_mfma_f32_16x16x32_bf16(ap00, b0, o[0][dt], 0, 0, 0);
      o[0][dt] = __builtin_amdgcn_mfma_f32_16x16x32_bf16(ap01, b1, o[0][dt], 0, 0, 0);
      o[1][dt] = __builtin_amdgcn_mfma_f32_16x16x32_bf16(ap10, b0, o[1][dt], 0, 0, 0);
      o[1][dt] = __builtin_amdgcn_mfma_f32_16x16x32_bf16(ap11, b1, o[1][dt], 0, 0, 0);
    }
    __syncthreads();   // drains prefetch; protects Ks/Vs[cur] for overwrite at it+2
  }

  // epilogue: reduce l across the 16 lanes sharing each row, divide, store
#pragma unroll
  for (int s = 0; s < 2; ++s)
#pragma unroll
    for (int r = 0; r < 4; ++r) {
#pragma unroll
      for (int off = 1; off < 16; off <<= 1)
        l_i[s][r] += __shfl_xor(l_i[s][r], off, 64);
      l_i[s][r] = 1.0f / l_i[s][r];
    }
#pragma unroll
  for (int s = 0; s < 2; ++s)
#pragma unroll
    for (int dt = 0; dt < 8; ++dt)
#pragma unroll
      for (int r = 0; r < 4; ++r) {
        int gr = q0 + wave * 32 + s * 16 + quad * 4 + r;
        int gc = h * DKD + dt * 16 + l15;
        Z[(size_t)gr * E_DIM + gc] = f32_to_bf16(o[s][dt][r] * l_i[s][r]);
      }
}

// ---------------- LayerNorm ----------------
__global__ __launch_bounds__(256) void ln_fwd(const float* __restrict__ Y,
                                              const float* __restrict__ g,
                                              const float* __restrict__ b,
                                              float* __restrict__ out) {
  const int row = blockIdx.x;
  const int tid = threadIdx.x;
  const float* y = Y + (size_t)row * E_DIM;
  f32x4 v = *(const f32x4*)(y + tid * 4);
  float s = v.x + v.y + v.z + v.w;
  float s2 = v.x * v.x + v.y * v.y + v.z * v.z + v.w * v.w;
#pragma unroll
  for (int off = 32; off > 0; off >>= 1) {
    s += __shfl_down(s, off, 64);
    s2 += __shfl_down(s2, off, 64);
  }
  __shared__ float red[8];
  __shared__ float mu_s, rs_s;
  const int wave = tid >> 6, lane = tid & 63;
  if (lane == 0) { red[wave] = s; red[4 + wave] = s2; }
  __syncthreads();
  if (tid == 0) {
    float ts = red[0] + red[1] + red[2] + red[3];
    float ts2 = red[4] + red[5] + red[6] + red[7];
    float mu = ts * (1.0f / E_DIM);
    float var = ts2 * (1.0f / E_DIM) - mu * mu;
    mu_s = mu;
    rs_s = rsqrtf(var + 1e-5f);
  }
  __syncthreads();
  const float mu = mu_s, rs = rs_s;
  f32x4 gg = *(const f32x4*)(g + tid * 4);
  f32x4 bb = *(const f32x4*)(b + tid * 4);
  f32x4 ov;
  ov.x = (v.x - mu) * rs * gg.x + bb.x;
  ov.y = (v.y - mu) * rs * gg.y + bb.y;
  ov.z = (v.z - mu) * rs * gg.z + bb.z;
  ov.w = (v.w - mu) * rs * gg.w + bb.w;
  *(f32x4*)(out + (size_t)row * E_DIM + tid * 4) = ov;
}

extern "C" void kernel_launch(void* const* d_in, const int* in_sizes, int n_in,
                              void* d_out, int out_size, void* d_ws, size_t ws_size,
                              hipStream_t stream) {
  const float* q   = (const float*)d_in[0];
  const float* k   = (const float*)d_in[1];
  const float* v   = (const float*)d_in[2];
  const int*  mask = (const int*)d_in[3];
  const float* gp  = (const float*)d_in[4];
  const float* Wq  = (const float*)d_in[5];
  const float* bq  = (const float*)d_in[6];
  const float* Wk  = (const float*)d_in[7];
  const float* bk  = (const float*)d_in[8];
  const float* Wv  = (const float*)d_in[9];
  const float* bv  = (const float*)d_in[10];
  const float* Wo  = (const float*)d_in[11];
  const float* bo  = (const float*)d_in[12];
  const float* lng = (const float*)d_in[13];
  const float* lnb = (const float*)d_in[14];

  char* ws = (char*)d_ws;
  const size_t MB = 1024 * 1024;
  unsigned short* WB = (unsigned short*)(ws + 0);        // Wq,Wk,Wv,Wo bf16 [0,8)
  unsigned short* XB = (unsigned short*)(ws + 8 * MB);   // q,k,v bf16 [8,32) dead after proj
  unsigned short* GT = (unsigned short*)(ws + 8 * MB);   // [8,40) built after proj
  unsigned short* QH = (unsigned short*)(ws + 40 * MB);  // [40,48)  Q proj (pre-scaled)
  unsigned short* KH = (unsigned short*)(ws + 48 * MB);  // [48,56)
  unsigned short* VT = (unsigned short*)(ws + 56 * MB);  // [56,64)  V^T [h*dk][s]
  unsigned short* ZB = (unsigned short*)(ws + 64 * MB);  // [64,72)
  float* YF = (float*)(ws + 72 * MB);                    // [72,88)

  const int nQKV = S_LEN * E_DIM;
  const int nW = E_DIM * E_DIM;
  cvt3<<<dim3(nQKV / 1024, 3), 256, 0, stream>>>(q, k, v, XB, nQKV);
  cvt4<<<dim3(nW / 1024, 4), 256, 0, stream>>>(Wq, Wk, Wv, Wo, WB, nW);

  proj_qkv<<<dim3(32, 8, 3), 256, 0, stream>>>(XB, WB, bq, bk, bv, QH, KH, VT);
  build_gt<<<dim3(64, 64), 256, 0, stream>>>(mask, gp, GT);   // overwrites XB
  attn_fwd<<<dim3(32, 8), 256, 0, stream>>>(QH, KH, VT, GT, ZB);
  out_proj<<<dim3(32, 8), 256, 0, stream>>>(ZB, WB + 3 * (size_t)nW, bo, q, YF);
  ln_fwd<<<S_LEN, 256, 0, stream>>>(YF, lng, lnb, (float*)d_out);
}

// Round 4
// 427.791 us; speedup vs baseline: 1.2681x; 1.1765x over previous
//
#include <hip/hip_runtime.h>

#define S_LEN 4096
#define E_DIM 1024
#define NH 8
#define DKD 128

typedef __attribute__((ext_vector_type(8))) short short8;
typedef __attribute__((ext_vector_type(4))) float f32x4;
typedef __attribute__((ext_vector_type(4))) unsigned short ushort4v;

#if __has_builtin(__builtin_amdgcn_exp2f)
#define EXP2F(x) __builtin_amdgcn_exp2f(x)
#else
#define EXP2F(x) exp2f(x)
#endif

// log2(e)/sqrt(128): folded into Q so QK^T scores are already in exp2 domain
#define QSCALE 0.12753819953924682f

__device__ __forceinline__ unsigned short f32_to_bf16(float f) {
  union { float f; unsigned u; } v; v.f = f;
  unsigned r = v.u + 0x7FFFu + ((v.u >> 16) & 1u);   // RNE
  return (unsigned short)(r >> 16);
}
__device__ __forceinline__ float bf16_to_f32(unsigned short h) {
  union { unsigned u; float f; } v; v.u = ((unsigned)h) << 16; return v.f;
}

__device__ __forceinline__ void gld_lds16(const unsigned short* g, unsigned short* l) {
  __builtin_amdgcn_global_load_lds(
      (const __attribute__((address_space(1))) void*)g,
      (__attribute__((address_space(3))) void*)l, 16, 0, 0);
}

// ---------------- fused fp32 -> bf16 conversion ----------------
__global__ __launch_bounds__(256) void cvt3(const float* __restrict__ a,
                                            const float* __restrict__ b,
                                            const float* __restrict__ c,
                                            unsigned short* __restrict__ dst, int n) {
  const float* src = (blockIdx.y == 0) ? a : (blockIdx.y == 1) ? b : c;
  unsigned short* d = dst + (size_t)blockIdx.y * n;
  int i = (blockIdx.x * 256 + threadIdx.x) * 4;
  if (i >= n) return;
  f32x4 v = *(const f32x4*)(src + i);
  uint2 pk;
  pk.x = (unsigned)f32_to_bf16(v.x) | ((unsigned)f32_to_bf16(v.y) << 16);
  pk.y = (unsigned)f32_to_bf16(v.z) | ((unsigned)f32_to_bf16(v.w) << 16);
  *(uint2*)(d + i) = pk;
}

__global__ __launch_bounds__(256) void cvt4(const float* __restrict__ a,
                                            const float* __restrict__ b,
                                            const float* __restrict__ c,
                                            const float* __restrict__ e,
                                            unsigned short* __restrict__ dst, int n) {
  const float* src = (blockIdx.y == 0) ? a : (blockIdx.y == 1) ? b
                   : (blockIdx.y == 2) ? c : e;
  unsigned short* d = dst + (size_t)blockIdx.y * n;
  int i = (blockIdx.x * 256 + threadIdx.x) * 4;
  if (i >= n) return;
  f32x4 v = *(const f32x4*)(src + i);
  uint2 pk;
  pk.x = (unsigned)f32_to_bf16(v.x) | ((unsigned)f32_to_bf16(v.y) << 16);
  pk.y = (unsigned)f32_to_bf16(v.z) | ((unsigned)f32_to_bf16(v.w) << 16);
  *(uint2*)(d + i) = pk;
}

// ---------------- Gt[t][s] = mask[s][t] ? bf16(gp[s][t]) : bf16(-1) ----------------
__global__ __launch_bounds__(256) void build_gt(const int* __restrict__ mask,
                                                const float* __restrict__ gp,
                                                unsigned short* __restrict__ Gt) {
  __shared__ unsigned short T[64 * 65];
  const int s0 = blockIdx.x * 64, t0 = blockIdx.y * 64;
  const int tid = threadIdx.x;
  const int r = tid >> 2;
  const int c0 = (tid & 3) * 16;
  const size_t base = (size_t)(s0 + r) * S_LEN + t0 + c0;
#pragma unroll
  for (int j = 0; j < 16; j += 4) {
    int4 m4 = *(const int4*)(mask + base + j);
    f32x4 g4 = *(const f32x4*)(gp + base + j);
    T[(c0 + j + 0) * 65 + r] = m4.x ? f32_to_bf16(g4.x) : (unsigned short)0xBF80;
    T[(c0 + j + 1) * 65 + r] = m4.y ? f32_to_bf16(g4.y) : (unsigned short)0xBF80;
    T[(c0 + j + 2) * 65 + r] = m4.z ? f32_to_bf16(g4.z) : (unsigned short)0xBF80;
    T[(c0 + j + 3) * 65 + r] = m4.w ? f32_to_bf16(g4.w) : (unsigned short)0xBF80;
  }
  __syncthreads();
  const int tr = tid >> 2;
  const int sc = (tid & 3) * 16;
  unsigned short tmp[16] __attribute__((aligned(16)));
#pragma unroll
  for (int j = 0; j < 16; ++j) tmp[j] = T[tr * 65 + sc + j];
  *(f32x4*)(Gt + (size_t)(t0 + tr) * S_LEN + s0 + sc) = *(const f32x4*)tmp;
  *(f32x4*)(Gt + (size_t)(t0 + tr) * S_LEN + s0 + sc + 8) = *(const f32x4*)(tmp + 8);
}

// XOR chunk swizzle, corrected for 64B row stride: slot = chunk ^ ((row>>1)&3).
// Staging lane L: row=L>>2, slot=L&3 -> global chunk = (L&3)^((L>>3)&3).
// Frag reader (row = ...16+l15, chunk = quad): slot = quad ^ ((l15>>1)&3).
#define SSW(lane) ((((lane) & 3) ^ (((lane) >> 3) & 3)) * 8)
#define KSWZ(quad, l15) ((((quad) ^ (((l15) >> 1) & 3))) * 8)

// ---------------- 128x128 bf16 GEMM core: C = A[M,K] * B[N,K]^T ----------------
__device__ __forceinline__ void gemm128_v3(const unsigned short* __restrict__ A,
                                           const unsigned short* __restrict__ B,
                                           int row0, int col0, int K,
                                           unsigned short* As, unsigned short* Bs,
                                           f32x4 acc[4][4]) {
  const int tid = threadIdx.x, lane = tid & 63, wave = tid >> 6;
  const int quad = lane >> 4, l15 = lane & 15;
  const int wm = (wave >> 1) * 64, wn = (wave & 1) * 64;
  const int sr = wave * 32 + (lane >> 2);
  const int ssw = SSW(lane);
  const int kswz = KSWZ(quad, l15);
  const unsigned short* gA = A + (size_t)(row0 + sr) * K + ssw;
  const unsigned short* gB = B + (size_t)(col0 + sr) * K + ssw;
  unsigned short* lA = As + wave * 32 * 32;
  unsigned short* lB = Bs + wave * 32 * 32;
  for (int k0 = 0; k0 < K; k0 += 32) {
    __syncthreads();
    gld_lds16(gA + k0, lA);
    gld_lds16(gA + k0 + (size_t)16 * K, lA + 16 * 32);
    gld_lds16(gB + k0, lB);
    gld_lds16(gB + k0 + (size_t)16 * K, lB + 16 * 32);
    __syncthreads();
    short8 a[4], b[4];
#pragma unroll
    for (int mt = 0; mt < 4; ++mt)
      a[mt] = *(const short8*)(As + (wm + mt * 16 + l15) * 32 + kswz);
#pragma unroll
    for (int nt = 0; nt < 4; ++nt)
      b[nt] = *(const short8*)(Bs + (wn + nt * 16 + l15) * 32 + kswz);
#pragma unroll
    for (int mt = 0; mt < 4; ++mt)
#pragma unroll
      for (int nt = 0; nt < 4; ++nt)
        acc[mt][nt] = __builtin_amdgcn_mfma_f32_16x16x32_bf16(a[mt], b[nt], acc[mt][nt], 0, 0, 0);
  }
}

// ---------------- QKV projection ----------------
__global__ __launch_bounds__(256) void proj_qkv(
    const unsigned short* __restrict__ xb, const unsigned short* __restrict__ Wb,
    const float* __restrict__ bq, const float* __restrict__ bk, const float* __restrict__ bv,
    unsigned short* __restrict__ Qh, unsigned short* __restrict__ Kh,
    unsigned short* __restrict__ Vt) {
  __shared__ __attribute__((aligned(16))) unsigned short As[128 * 32];
  __shared__ __attribute__((aligned(16))) unsigned short Bs[128 * 32];
  const int z = blockIdx.z;
  const unsigned short* X = xb + (size_t)z * S_LEN * E_DIM;
  const unsigned short* W = Wb + (size_t)z * E_DIM * E_DIM;
  const float* bias = (z == 0) ? bq : (z == 1) ? bk : bv;
  const f32x4 zero4 = {0.f, 0.f, 0.f, 0.f};
  f32x4 acc[4][4];
#pragma unroll
  for (int i = 0; i < 4; ++i)
#pragma unroll
    for (int j = 0; j < 4; ++j) acc[i][j] = zero4;
  const int lane = threadIdx.x & 63, wave = threadIdx.x >> 6;
  const int quad = lane >> 4, l15 = lane & 15;
  const int wm = (wave >> 1) * 64, wn = (wave & 1) * 64;
  if (z < 2) {
    const int row0 = blockIdx.y * 128;   // e
    const int col0 = blockIdx.x * 128;   // s
    gemm128_v3(W, X, row0, col0, E_DIM, As, Bs, acc);
    unsigned short* Out = (z == 0) ? Qh : Kh;
    const float scale = (z == 0) ? QSCALE : 1.0f;
#pragma unroll
    for (int mt = 0; mt < 4; ++mt) {
      int ge = row0 + wm + mt * 16 + quad * 4;
      f32x4 b4 = *(const f32x4*)(bias + ge);
#pragma unroll
      for (int nt = 0; nt < 4; ++nt) {
        int gs = col0 + wn + nt * 16 + l15;
        ushort4v pk;
#pragma unroll
        for (int r = 0; r < 4; ++r) pk[r] = f32_to_bf16((acc[mt][nt][r] + b4[r]) * scale);
        *(ushort4v*)(Out + (size_t)gs * E_DIM + ge) = pk;
      }
    }
  } else {
    const int row0 = blockIdx.x * 128;   // s
    const int col0 = blockIdx.y * 128;   // e
    gemm128_v3(X, W, row0, col0, E_DIM, As, Bs, acc);
#pragma unroll
    for (int nt = 0; nt < 4; ++nt) {
      int ge = col0 + wn + nt * 16 + l15;
      float bv_ = bias[ge];
#pragma unroll
      for (int mt = 0; mt < 4; ++mt) {
        int gs = row0 + wm + mt * 16 + quad * 4;
        ushort4v pk;
#pragma unroll
        for (int r = 0; r < 4; ++r) pk[r] = f32_to_bf16(acc[mt][nt][r] + bv_);
        *(ushort4v*)(Vt + (size_t)ge * S_LEN + gs) = pk;   // V^T [e][s]
      }
    }
  }
}

// ---------------- output projection + bias + residual ----------------
__global__ __launch_bounds__(256) void out_proj(
    const unsigned short* __restrict__ Zb, const unsigned short* __restrict__ Wob,
    const float* __restrict__ bo, const float* __restrict__ resid,
    float* __restrict__ Y) {
  __shared__ __attribute__((aligned(16))) unsigned short As[128 * 32];
  __shared__ __attribute__((aligned(16))) unsigned short Bs[128 * 32];
  const int row0 = blockIdx.y * 128;  // e
  const int col0 = blockIdx.x * 128;  // s
  const f32x4 zero4 = {0.f, 0.f, 0.f, 0.f};
  f32x4 acc[4][4];
#pragma unroll
  for (int i = 0; i < 4; ++i)
#pragma unroll
    for (int j = 0; j < 4; ++j) acc[i][j] = zero4;
  gemm128_v3(Wob, Zb, row0, col0, E_DIM, As, Bs, acc);
  const int lane = threadIdx.x & 63, wave = threadIdx.x >> 6;
  const int quad = lane >> 4, l15 = lane & 15;
  const int wm = (wave >> 1) * 64, wn = (wave & 1) * 64;
#pragma unroll
  for (int mt = 0; mt < 4; ++mt) {
    int ge = row0 + wm + mt * 16 + quad * 4;
    f32x4 b4 = *(const f32x4*)(bo + ge);
#pragma unroll
    for (int nt = 0; nt < 4; ++nt) {
      int gs = col0 + wn + nt * 16 + l15;
      f32x4 r4 = *(const f32x4*)(resid + (size_t)gs * E_DIM + ge);
      f32x4 ov = acc[mt][nt] + b4 + r4;
      *(f32x4*)(Y + (size_t)gs * E_DIM + ge) = ov;
    }
  }
}

// ---------------- flash attention, t-split in 2 for occupancy ----------------
// grid (32 qt, 8 h, 2 ts) = 512 blocks -> 2 blocks/CU (LDS 66560 B).
// Each block: 128 q-rows x 2048 keys (32 iters). Partials are additive
// (fixed-base softmax): O-partial bf16 + l-partial fp32, merged by combine().
__global__ __launch_bounds__(256, 2) void attn_fwd(
    const unsigned short* __restrict__ Qh, const unsigned short* __restrict__ Kh,
    const unsigned short* __restrict__ Vt, const unsigned short* __restrict__ Gt,
    unsigned short* __restrict__ OP, float* __restrict__ LP) {
  __shared__ __attribute__((aligned(16))) unsigned short Ks[2][4][64][32];
  __shared__ __attribute__((aligned(16))) unsigned short Vs[2][128][32];
  __shared__ __attribute__((aligned(16))) unsigned short Ps[4][32 * 68];
  const int qt = blockIdx.x, h = blockIdx.y, ts = blockIdx.z;
  const int q0 = qt * 128;
  const int tbase = ts * 2048;
  const int tid = threadIdx.x;
  const int wave = tid >> 6, lane = tid & 63;
  const int quad = lane >> 4, l15 = lane & 15;
  const int srow = lane >> 2;
  const int ssw = SSW(lane);
  const int kswz = KSWZ(quad, l15);
  const int hv = wave & 1, db = wave >> 1;

  const unsigned short* gK =
      Kh + (size_t)(tbase + srow) * E_DIM + h * DKD + wave * 32 + ssw;
  const unsigned short* gV =
      Vt + (size_t)(h * DKD + db * 64 + srow) * S_LEN + tbase + hv * 32 + ssw;

  // Q fragments in registers (Qh[s][e], Q pre-scaled by QSCALE)
  short8 aq[2][4];
#pragma unroll
  for (int s = 0; s < 2; ++s) {
    const unsigned short* qp =
        Qh + (size_t)(q0 + wave * 32 + s * 16 + l15) * E_DIM + h * DKD;
#pragma unroll
    for (int kk = 0; kk < 4; ++kk) aq[s][kk] = *(const short8*)(qp + kk * 32 + quad * 8);
  }

  float l_i[2][4];
#pragma unroll
  for (int s = 0; s < 2; ++s)
#pragma unroll
    for (int r = 0; r < 4; ++r) l_i[s][r] = 0.0f;
  const f32x4 zero4 = {0.f, 0.f, 0.f, 0.f};
  f32x4 o[2][8];
#pragma unroll
  for (int s = 0; s < 2; ++s)
#pragma unroll
    for (int d = 0; d < 8; ++d) o[s][d] = zero4;

  // prologue: stage K0 -> Ks[0], V0 -> Vs
#pragma unroll
  for (int c = 0; c < 4; ++c) {
    gld_lds16(gK + (size_t)(c * 16) * E_DIM, &Ks[0][wave][c * 16][0]);
    gld_lds16(gV + (size_t)(c * 16) * S_LEN, &Vs[hv][db * 64 + c * 16][0]);
  }
  __syncthreads();

  const int srow0 = q0 + wave * 32 + quad * 4;

  for (int it = 0; it < 32; ++it) {
    const int t0 = it * 64;                 // local offset within this t-half
    const int cur = it & 1, nxt = 1 - cur;

    // Gt loads first (consumed mid-loop; don't let their wait drain prefetch)
    ushort4v g4[2][4];
#pragma unroll
    for (int s = 0; s < 2; ++s)
#pragma unroll
      for (int nt = 0; nt < 4; ++nt) {
        int tg = tbase + t0 + nt * 16 + l15;
        g4[s][nt] = *(const ushort4v*)(Gt + (size_t)tg * S_LEN + srow0 + s * 16);
      }

    // prefetch K(t+1) into other K buffer
    if (it + 1 < 32) {
#pragma unroll
      for (int c = 0; c < 4; ++c)
        gld_lds16(gK + (size_t)(t0 + 64 + c * 16) * E_DIM, &Ks[nxt][wave][c * 16][0]);
    }

    // S' = Q K^T (exp2 domain)
    f32x4 sA[2][4];
#pragma unroll
    for (int nt = 0; nt < 4; ++nt) { sA[0][nt] = zero4; sA[1][nt] = zero4; }
#pragma unroll
    for (int nt = 0; nt < 4; ++nt)
#pragma unroll
      for (int kk = 0; kk < 4; ++kk) {
        short8 bK = *(const short8*)&Ks[cur][kk][nt * 16 + l15][kswz];
        sA[0][nt] = __builtin_amdgcn_mfma_f32_16x16x32_bf16(aq[0][kk], bK, sA[0][nt], 0, 0, 0);
        sA[1][nt] = __builtin_amdgcn_mfma_f32_16x16x32_bf16(aq[1][kk], bK, sA[1][nt], 0, 0, 0);
      }

    // fixed-base softmax: p = exp2(s'), masked -> 0
#pragma unroll
    for (int s = 0; s < 2; ++s)
#pragma unroll
      for (int nt = 0; nt < 4; ++nt)
#pragma unroll
        for (int r = 0; r < 4; ++r) {
          float gv = bf16_to_f32(g4[s][nt][r]);
          float x = (gv < 0.0f) ? -1e9f : sA[s][nt][r];
          float e = EXP2F(x);
          l_i[s][r] += e;
          union { float f; unsigned u; } pb; pb.f = e * gv;
          Ps[wave][(s * 16 + quad * 4 + r) * 68 + nt * 16 + l15] =
              (unsigned short)((pb.u + 0x8000u) >> 16);
        }

    // O += P V  (Vs single-buffered; per-wave Ps, no barrier needed)
    short8 ap00 = *(const short8*)&Ps[wave][l15 * 68 + quad * 8];
    short8 ap01 = *(const short8*)&Ps[wave][l15 * 68 + 32 + quad * 8];
    short8 ap10 = *(const short8*)&Ps[wave][(16 + l15) * 68 + quad * 8];
    short8 ap11 = *(const short8*)&Ps[wave][(16 + l15) * 68 + 32 + quad * 8];
#pragma unroll
    for (int dt = 0; dt < 8; ++dt) {
      short8 b0 = *(const short8*)&Vs[0][dt * 16 + l15][kswz];
      short8 b1 = *(const short8*)&Vs[1][dt * 16 + l15][kswz];
      o[0][dt] = __builtin_amdgcn_mfma_f32_16x16x32_bf16(ap00, b0, o[0][dt], 0, 0, 0);
      o[0][dt] = __builtin_amdgcn_mfma_f32_16x16x32_bf16(ap01, b1, o[0][dt], 0, 0, 0);
      o[1][dt] = __builtin_amdgcn_mfma_f32_16x16x32_bf16(ap10, b0, o[1][dt], 0, 0, 0);
      o[1][dt] = __builtin_amdgcn_mfma_f32_16x16x32_bf16(ap11, b1, o[1][dt], 0, 0, 0);
    }
    __syncthreads();    // waves done reading Vs/Ks[cur]; drains K prefetch
    if (it + 1 < 32) {
#pragma unroll
      for (int c = 0; c < 4; ++c)
        gld_lds16(gV + (size_t)(c * 16) * S_LEN + t0 + 64, &Vs[hv][db * 64 + c * 16][0]);
      __syncthreads();  // drain V(t+1)
    }
  }

  // epilogue: reduce l over the 16 lanes of each row; write partials
#pragma unroll
  for (int s = 0; s < 2; ++s)
#pragma unroll
    for (int r = 0; r < 4; ++r) {
#pragma unroll
      for (int off = 1; off < 16; off <<= 1)
        l_i[s][r] += __shfl_xor(l_i[s][r], off, 64);
    }
  if (l15 == 0) {
#pragma unroll
    for (int s = 0; s < 2; ++s)
#pragma unroll
      for (int r = 0; r < 4; ++r) {
        int gr = srow0 + s * 16 + r;
        LP[((size_t)ts * NH + h) * S_LEN + gr] = l_i[s][r];
      }
  }
  unsigned short* op = OP + (size_t)ts * S_LEN * E_DIM;
#pragma unroll
  for (int s = 0; s < 2; ++s)
#pragma unroll
    for (int dt = 0; dt < 8; ++dt)
#pragma unroll
      for (int r = 0; r < 4; ++r) {
        int gr = q0 + wave * 32 + s * 16 + quad * 4 + r;
        int gc = h * DKD + dt * 16 + l15;
        op[(size_t)gr * E_DIM + gc] = f32_to_bf16(o[s][dt][r]);
      }
}

// ---------------- combine t-split partials: Z = (O0+O1)/(l0+l1) ----------------
__global__ __launch_bounds__(256) void combine(const unsigned short* __restrict__ OP,
                                               const float* __restrict__ LP,
                                               unsigned short* __restrict__ Z) {
  const int s = blockIdx.x;
  const int e0 = threadIdx.x * 4;
  const int h = e0 >> 7;
  const float l = LP[(size_t)h * S_LEN + s] + LP[(size_t)(NH + h) * S_LEN + s];
  const float inv = 1.0f / l;
  ushort4v a = *(const ushort4v*)(OP + (size_t)s * E_DIM + e0);
  ushort4v b = *(const ushort4v*)(OP + (size_t)S_LEN * E_DIM + (size_t)s * E_DIM + e0);
  ushort4v pk;
#pragma unroll
  for (int j = 0; j < 4; ++j)
    pk[j] = f32_to_bf16((bf16_to_f32(a[j]) + bf16_to_f32(b[j])) * inv);
  *(ushort4v*)(Z + (size_t)s * E_DIM + e0) = pk;
}

// ---------------- LayerNorm ----------------
__global__ __launch_bounds__(256) void ln_fwd(const float* __restrict__ Y,
                                              const float* __restrict__ g,
                                              const float* __restrict__ b,
                                              float* __restrict__ out) {
  const int row = blockIdx.x;
  const int tid = threadIdx.x;
  const float* y = Y + (size_t)row * E_DIM;
  f32x4 v = *(const f32x4*)(y + tid * 4);
  float s = v.x + v.y + v.z + v.w;
  float s2 = v.x * v.x + v.y * v.y + v.z * v.z + v.w * v.w;
#pragma unroll
  for (int off = 32; off > 0; off >>= 1) {
    s += __shfl_down(s, off, 64);
    s2 += __shfl_down(s2, off, 64);
  }
  __shared__ float red[8];
  __shared__ float mu_s, rs_s;
  const int wave = tid >> 6, lane = tid & 63;
  if (lane == 0) { red[wave] = s; red[4 + wave] = s2; }
  __syncthreads();
  if (tid == 0) {
    float ts = red[0] + red[1] + red[2] + red[3];
    float ts2 = red[4] + red[5] + red[6] + red[7];
    float mu = ts * (1.0f / E_DIM);
    float var = ts2 * (1.0f / E_DIM) - mu * mu;
    mu_s = mu;
    rs_s = rsqrtf(var + 1e-5f);
  }
  __syncthreads();
  const float mu = mu_s, rs = rs_s;
  f32x4 gg = *(const f32x4*)(g + tid * 4);
  f32x4 bb = *(const f32x4*)(b + tid * 4);
  f32x4 ov;
  ov.x = (v.x - mu) * rs * gg.x + bb.x;
  ov.y = (v.y - mu) * rs * gg.y + bb.y;
  ov.z = (v.z - mu) * rs * gg.z + bb.z;
  ov.w = (v.w - mu) * rs * gg.w + bb.w;
  *(f32x4*)(out + (size_t)row * E_DIM + tid * 4) = ov;
}

extern "C" void kernel_launch(void* const* d_in, const int* in_sizes, int n_in,
                              void* d_out, int out_size, void* d_ws, size_t ws_size,
                              hipStream_t stream) {
  const float* q   = (const float*)d_in[0];
  const float* k   = (const float*)d_in[1];
  const float* v   = (const float*)d_in[2];
  const int*  mask = (const int*)d_in[3];
  const float* gp  = (const float*)d_in[4];
  const float* Wq  = (const float*)d_in[5];
  const float* bq  = (const float*)d_in[6];
  const float* Wk  = (const float*)d_in[7];
  const float* bk  = (const float*)d_in[8];
  const float* Wv  = (const float*)d_in[9];
  const float* bv  = (const float*)d_in[10];
  const float* Wo  = (const float*)d_in[11];
  const float* bo  = (const float*)d_in[12];
  const float* lng = (const float*)d_in[13];
  const float* lnb = (const float*)d_in[14];

  char* ws = (char*)d_ws;
  const size_t MB = 1024 * 1024;
  // layout, 80.25 MB peak (lifetimes disjoint where overlapped):
  unsigned short* WB = (unsigned short*)(ws + 0);        // Wq,Wk,Wv,Wo bf16 [0,8)
  unsigned short* XB = (unsigned short*)(ws + 8 * MB);   // q,k,v bf16 [8,32) dead after proj
  unsigned short* GT = (unsigned short*)(ws + 8 * MB);   // [8,40) built after proj
  unsigned short* QH = (unsigned short*)(ws + 40 * MB);  // [40,48) dead after attn
  unsigned short* KH = (unsigned short*)(ws + 48 * MB);  // [48,56) dead after attn
  unsigned short* VT = (unsigned short*)(ws + 56 * MB);  // [56,64) dead after attn
  float* YF = (float*)(ws + 40 * MB);                    // [40,56) written by out_proj
  unsigned short* ZB = (unsigned short*)(ws + 56 * MB);  // [56,64) written by combine
  unsigned short* OP = (unsigned short*)(ws + 64 * MB);  // [64,80) O-partials (2x8MB bf16)
  float* LPb = (float*)(ws + 80 * MB);                   // [80,80.25) l-partials

  const int nQKV = S_LEN * E_DIM;
  const int nW = E_DIM * E_DIM;
  cvt3<<<dim3(nQKV / 1024, 3), 256, 0, stream>>>(q, k, v, XB, nQKV);
  cvt4<<<dim3(nW / 1024, 4), 256, 0, stream>>>(Wq, Wk, Wv, Wo, WB, nW);

  proj_qkv<<<dim3(32, 8, 3), 256, 0, stream>>>(XB, WB, bq, bk, bv, QH, KH, VT);
  build_gt<<<dim3(64, 64), 256, 0, stream>>>(mask, gp, GT);   // overwrites XB
  attn_fwd<<<dim3(32, 8, 2), 256, 0, stream>>>(QH, KH, VT, GT, OP, LPb);
  combine<<<S_LEN, 256, 0, stream>>>(OP, LPb, ZB);
  out_proj<<<dim3(32, 8), 256, 0, stream>>>(ZB, WB + 3 * (size_t)nW, bo, q, YF);
  ln_fwd<<<S_LEN, 256, 0, stream>>>(YF, lng, lnb, (float*)d_out);
}

// Round 5
// 418.086 us; speedup vs baseline: 1.2976x; 1.0232x over previous
//
#include <hip/hip_runtime.h>

#define S_LEN 4096
#define E_DIM 1024
#define NH 8
#define DKD 128

typedef __attribute__((ext_vector_type(8))) short short8;
typedef __attribute__((ext_vector_type(4))) float f32x4;
typedef __attribute__((ext_vector_type(4))) unsigned short ushort4v;

#if __has_builtin(__builtin_amdgcn_exp2f)
#define EXP2F(x) __builtin_amdgcn_exp2f(x)
#else
#define EXP2F(x) exp2f(x)
#endif

// log2(e)/sqrt(128): folded into Q so QK^T scores are already in exp2 domain
#define QSCALE 0.12753819953924682f

__device__ __forceinline__ unsigned short f32_to_bf16(float f) {
  union { float f; unsigned u; } v; v.f = f;
  unsigned r = v.u + 0x7FFFu + ((v.u >> 16) & 1u);   // RNE
  return (unsigned short)(r >> 16);
}
__device__ __forceinline__ float bf16_to_f32(unsigned short h) {
  union { unsigned u; float f; } v; v.u = ((unsigned)h) << 16; return v.f;
}

__device__ __forceinline__ void gld_lds16(const unsigned short* g, unsigned short* l) {
  __builtin_amdgcn_global_load_lds(
      (const __attribute__((address_space(1))) void*)g,
      (__attribute__((address_space(3))) void*)l, 16, 0, 0);
}

// ---------------- fused fp32 -> bf16 conversion, all 7 tensors, 1 launch ----------------
// y: 0,1,2 = q,k,v (4M elems) -> XB; 3,4,5 = Wq,Wk,Wv -> ws+2MB..; 6 = Wo -> ws+0
__global__ __launch_bounds__(256) void cvt_all(const float* __restrict__ q,
                                               const float* __restrict__ k,
                                               const float* __restrict__ v,
                                               const float* __restrict__ wq,
                                               const float* __restrict__ wk,
                                               const float* __restrict__ wv,
                                               const float* __restrict__ wo,
                                               unsigned short* __restrict__ wsbase) {
  const int y = blockIdx.y;
  const int n = (y < 3) ? (S_LEN * E_DIM) : (E_DIM * E_DIM);
  int i = (blockIdx.x * 256 + threadIdx.x) * 4;
  if (i >= n) return;
  const float* src;
  unsigned short* d;
  const size_t MBe = 512 * 1024;  // elems per MB
  switch (y) {
    case 0: src = q;  d = wsbase + 8 * MBe; break;
    case 1: src = k;  d = wsbase + 16 * MBe; break;
    case 2: src = v;  d = wsbase + 24 * MBe; break;
    case 3: src = wq; d = wsbase + 2 * MBe; break;
    case 4: src = wk; d = wsbase + 4 * MBe; break;
    case 5: src = wv; d = wsbase + 6 * MBe; break;
    default: src = wo; d = wsbase; break;
  }
  f32x4 val = *(const f32x4*)(src + i);
  uint2 pk;
  pk.x = (unsigned)f32_to_bf16(val.x) | ((unsigned)f32_to_bf16(val.y) << 16);
  pk.y = (unsigned)f32_to_bf16(val.z) | ((unsigned)f32_to_bf16(val.w) << 16);
  *(uint2*)(d + i) = pk;
}

// ---------------- Gt[t][s] = mask[s][t] ? bf16(gp[s][t]) : bf16(-1) ----------------
__global__ __launch_bounds__(256) void build_gt(const int* __restrict__ mask,
                                                const float* __restrict__ gp,
                                                unsigned short* __restrict__ Gt) {
  __shared__ unsigned short T[64 * 65];
  const int s0 = blockIdx.x * 64, t0 = blockIdx.y * 64;
  const int tid = threadIdx.x;
  const int r = tid >> 2;
  const int c0 = (tid & 3) * 16;
  const size_t base = (size_t)(s0 + r) * S_LEN + t0 + c0;
#pragma unroll
  for (int j = 0; j < 16; j += 4) {
    int4 m4 = *(const int4*)(mask + base + j);
    f32x4 g4 = *(const f32x4*)(gp + base + j);
    T[(c0 + j + 0) * 65 + r] = m4.x ? f32_to_bf16(g4.x) : (unsigned short)0xBF80;
    T[(c0 + j + 1) * 65 + r] = m4.y ? f32_to_bf16(g4.y) : (unsigned short)0xBF80;
    T[(c0 + j + 2) * 65 + r] = m4.z ? f32_to_bf16(g4.z) : (unsigned short)0xBF80;
    T[(c0 + j + 3) * 65 + r] = m4.w ? f32_to_bf16(g4.w) : (unsigned short)0xBF80;
  }
  __syncthreads();
  const int tr = tid >> 2;
  const int sc = (tid & 3) * 16;
  unsigned short tmp[16] __attribute__((aligned(16)));
#pragma unroll
  for (int j = 0; j < 16; ++j) tmp[j] = T[tr * 65 + sc + j];
  *(f32x4*)(Gt + (size_t)(t0 + tr) * S_LEN + s0 + sc) = *(const f32x4*)tmp;
  *(f32x4*)(Gt + (size_t)(t0 + tr) * S_LEN + s0 + sc + 8) = *(const f32x4*)(tmp + 8);
}

// XOR chunk swizzle for 64B-row LDS tiles: stored slot = chunk ^ ((row>>1)&3).
#define SSW(lane) ((((lane) & 3) ^ (((lane) >> 3) & 3)) * 8)
#define KSWZ(quad, l15) ((((quad) ^ (((l15) >> 1) & 3))) * 8)

// ---------------- 128x128 bf16 GEMM core: C = A[M,K] * B[N,K]^T ----------------
__device__ __forceinline__ void gemm128_v3(const unsigned short* __restrict__ A,
                                           const unsigned short* __restrict__ B,
                                           int row0, int col0, int K,
                                           unsigned short* As, unsigned short* Bs,
                                           f32x4 acc[4][4]) {
  const int tid = threadIdx.x, lane = tid & 63, wave = tid >> 6;
  const int quad = lane >> 4, l15 = lane & 15;
  const int wm = (wave >> 1) * 64, wn = (wave & 1) * 64;
  const int sr = wave * 32 + (lane >> 2);
  const int ssw = SSW(lane);
  const int kswz = KSWZ(quad, l15);
  const unsigned short* gA = A + (size_t)(row0 + sr) * K + ssw;
  const unsigned short* gB = B + (size_t)(col0 + sr) * K + ssw;
  unsigned short* lA = As + wave * 32 * 32;
  unsigned short* lB = Bs + wave * 32 * 32;
  for (int k0 = 0; k0 < K; k0 += 32) {
    __syncthreads();
    gld_lds16(gA + k0, lA);
    gld_lds16(gA + k0 + (size_t)16 * K, lA + 16 * 32);
    gld_lds16(gB + k0, lB);
    gld_lds16(gB + k0 + (size_t)16 * K, lB + 16 * 32);
    __syncthreads();
    short8 a[4], b[4];
#pragma unroll
    for (int mt = 0; mt < 4; ++mt)
      a[mt] = *(const short8*)(As + (wm + mt * 16 + l15) * 32 + kswz);
#pragma unroll
    for (int nt = 0; nt < 4; ++nt)
      b[nt] = *(const short8*)(Bs + (wn + nt * 16 + l15) * 32 + kswz);
#pragma unroll
    for (int mt = 0; mt < 4; ++mt)
#pragma unroll
      for (int nt = 0; nt < 4; ++nt)
        acc[mt][nt] = __builtin_amdgcn_mfma_f32_16x16x32_bf16(a[mt], b[nt], acc[mt][nt], 0, 0, 0);
  }
}

// ---------------- QKV projection ----------------
__global__ __launch_bounds__(256) void proj_qkv(
    const unsigned short* __restrict__ xb, const unsigned short* __restrict__ Wb,
    const float* __restrict__ bq, const float* __restrict__ bk, const float* __restrict__ bv,
    unsigned short* __restrict__ Qh, unsigned short* __restrict__ Kh,
    unsigned short* __restrict__ Vt) {
  __shared__ __attribute__((aligned(16))) unsigned short As[128 * 32];
  __shared__ __attribute__((aligned(16))) unsigned short Bs[128 * 32];
  const int z = blockIdx.z;
  const unsigned short* X = xb + (size_t)z * S_LEN * E_DIM;
  const unsigned short* W = Wb + (size_t)z * E_DIM * E_DIM;
  const float* bias = (z == 0) ? bq : (z == 1) ? bk : bv;
  const f32x4 zero4 = {0.f, 0.f, 0.f, 0.f};
  f32x4 acc[4][4];
#pragma unroll
  for (int i = 0; i < 4; ++i)
#pragma unroll
    for (int j = 0; j < 4; ++j) acc[i][j] = zero4;
  const int lane = threadIdx.x & 63, wave = threadIdx.x >> 6;
  const int quad = lane >> 4, l15 = lane & 15;
  const int wm = (wave >> 1) * 64, wn = (wave & 1) * 64;
  if (z < 2) {
    const int row0 = blockIdx.y * 128;   // e
    const int col0 = blockIdx.x * 128;   // s
    gemm128_v3(W, X, row0, col0, E_DIM, As, Bs, acc);
    unsigned short* Out = (z == 0) ? Qh : Kh;
    const float scale = (z == 0) ? QSCALE : 1.0f;
#pragma unroll
    for (int mt = 0; mt < 4; ++mt) {
      int ge = row0 + wm + mt * 16 + quad * 4;
      f32x4 b4 = *(const f32x4*)(bias + ge);
#pragma unroll
      for (int nt = 0; nt < 4; ++nt) {
        int gs = col0 + wn + nt * 16 + l15;
        ushort4v pk;
#pragma unroll
        for (int r = 0; r < 4; ++r) pk[r] = f32_to_bf16((acc[mt][nt][r] + b4[r]) * scale);
        *(ushort4v*)(Out + (size_t)gs * E_DIM + ge) = pk;
      }
    }
  } else {
    const int row0 = blockIdx.x * 128;   // s
    const int col0 = blockIdx.y * 128;   // e
    gemm128_v3(X, W, row0, col0, E_DIM, As, Bs, acc);
#pragma unroll
    for (int nt = 0; nt < 4; ++nt) {
      int ge = col0 + wn + nt * 16 + l15;
      float bv_ = bias[ge];
#pragma unroll
      for (int mt = 0; mt < 4; ++mt) {
        int gs = row0 + wm + mt * 16 + quad * 4;
        ushort4v pk;
#pragma unroll
        for (int r = 0; r < 4; ++r) pk[r] = f32_to_bf16(acc[mt][nt][r] + bv_);
        *(ushort4v*)(Vt + (size_t)ge * S_LEN + gs) = pk;   // V^T [e][s]
      }
    }
  }
}

// ---------------- output projection + bias + residual: 64e x 128s tiles ----------------
// grid (32 s-tiles, 16 e-tiles) = 512 blocks -> 2/CU.
__global__ __launch_bounds__(256) void out_proj(
    const unsigned short* __restrict__ Zb, const unsigned short* __restrict__ Wob,
    const float* __restrict__ bo, const float* __restrict__ resid,
    float* __restrict__ Y) {
  __shared__ __attribute__((aligned(16))) unsigned short As[64 * 32];
  __shared__ __attribute__((aligned(16))) unsigned short Bs[128 * 32];
  const int row0 = blockIdx.y * 64;   // e
  const int col0 = blockIdx.x * 128;  // s
  const int tid = threadIdx.x, lane = tid & 63, wave = tid >> 6;
  const int quad = lane >> 4, l15 = lane & 15;
  const int wm = (wave >> 1) * 32, wn = (wave & 1) * 64;
  const int ssw = SSW(lane);
  const int kswz = KSWZ(quad, l15);
  const f32x4 zero4 = {0.f, 0.f, 0.f, 0.f};
  f32x4 acc[2][4];
#pragma unroll
  for (int i = 0; i < 2; ++i)
#pragma unroll
    for (int j = 0; j < 4; ++j) acc[i][j] = zero4;
  const unsigned short* gA = Wob + (size_t)(row0 + wave * 16 + (lane >> 2)) * E_DIM + ssw;
  const unsigned short* gB = Zb + (size_t)(col0 + wave * 32 + (lane >> 2)) * E_DIM + ssw;
  unsigned short* lA = As + wave * 16 * 32;
  unsigned short* lB = Bs + wave * 32 * 32;
  for (int k0 = 0; k0 < E_DIM; k0 += 32) {
    __syncthreads();
    gld_lds16(gA + k0, lA);
    gld_lds16(gB + k0, lB);
    gld_lds16(gB + k0 + (size_t)16 * E_DIM, lB + 16 * 32);
    __syncthreads();
    short8 a[2], b[4];
#pragma unroll
    for (int mt = 0; mt < 2; ++mt)
      a[mt] = *(const short8*)(As + (wm + mt * 16 + l15) * 32 + kswz);
#pragma unroll
    for (int nt = 0; nt < 4; ++nt)
      b[nt] = *(const short8*)(Bs + (wn + nt * 16 + l15) * 32 + kswz);
#pragma unroll
    for (int mt = 0; mt < 2; ++mt)
#pragma unroll
      for (int nt = 0; nt < 4; ++nt)
        acc[mt][nt] = __builtin_amdgcn_mfma_f32_16x16x32_bf16(a[mt], b[nt], acc[mt][nt], 0, 0, 0);
  }
#pragma unroll
  for (int mt = 0; mt < 2; ++mt) {
    int ge = row0 + wm + mt * 16 + quad * 4;
    f32x4 b4 = *(const f32x4*)(bo + ge);
#pragma unroll
    for (int nt = 0; nt < 4; ++nt) {
      int gs = col0 + wn + nt * 16 + l15;
      f32x4 r4 = *(const f32x4*)(resid + (size_t)gs * E_DIM + ge);
      f32x4 ov = acc[mt][nt] + b4 + r4;
      *(f32x4*)(Y + (size_t)gs * E_DIM + ge) = ov;
    }
  }
}

// ---------------- flash attention, t-split x3, single-buffered K/V ----------------
// grid (32 qt, 8 h, 3 ts) = 768 blocks -> 3 blocks/CU (LDS 50176 B).
// t-ranges: [0,1408), [1408,2752), [2752,4096) -> 22/21/21 iters of 64 keys.
// Per iter: QK(Ks) -> barrierA -> issue K(t+1) -> softmax+P -> PV(Vs) -> barrierB
// -> issue V(t+1). Each stage drains one barrier later, in the shadow of compute.
__global__ __launch_bounds__(256, 3) void attn_fwd(
    const unsigned short* __restrict__ Qh, const unsigned short* __restrict__ Kh,
    const unsigned short* __restrict__ Vt, const unsigned short* __restrict__ Gt,
    unsigned short* __restrict__ OP, float* __restrict__ LP) {
  __shared__ __attribute__((aligned(16))) unsigned short Ks[4][64][32];
  __shared__ __attribute__((aligned(16))) unsigned short Vs[2][128][32];
  __shared__ __attribute__((aligned(16))) unsigned short Ps[4][32 * 68];
  const int qt = blockIdx.x, h = blockIdx.y, ts = blockIdx.z;
  const int q0 = qt * 128;
  const int tbase = (ts == 0) ? 0 : (1408 + 1344 * (ts - 1));
  const int niter = (ts == 0) ? 22 : 21;
  const int tid = threadIdx.x;
  const int wave = tid >> 6, lane = tid & 63;
  const int quad = lane >> 4, l15 = lane & 15;
  const int srow = lane >> 2;
  const int ssw = SSW(lane);
  const int kswz = KSWZ(quad, l15);
  const int hv = wave & 1, db = wave >> 1;

  const unsigned short* gK =
      Kh + (size_t)(tbase + srow) * E_DIM + h * DKD + wave * 32 + ssw;
  const unsigned short* gV =
      Vt + (size_t)(h * DKD + db * 64 + srow) * S_LEN + tbase + hv * 32 + ssw;

  // Q fragments in registers (Qh[s][e], Q pre-scaled by QSCALE)
  short8 aq[2][4];
#pragma unroll
  for (int s = 0; s < 2; ++s) {
    const unsigned short* qp =
        Qh + (size_t)(q0 + wave * 32 + s * 16 + l15) * E_DIM + h * DKD;
#pragma unroll
    for (int kk = 0; kk < 4; ++kk) aq[s][kk] = *(const short8*)(qp + kk * 32 + quad * 8);
  }

  float l_i[2][4];
#pragma unroll
  for (int s = 0; s < 2; ++s)
#pragma unroll
    for (int r = 0; r < 4; ++r) l_i[s][r] = 0.0f;
  const f32x4 zero4 = {0.f, 0.f, 0.f, 0.f};
  f32x4 o[2][8];
#pragma unroll
  for (int s = 0; s < 2; ++s)
#pragma unroll
    for (int d = 0; d < 8; ++d) o[s][d] = zero4;

  // prologue: stage tile 0
#pragma unroll
  for (int c = 0; c < 4; ++c) {
    gld_lds16(gK + (size_t)(c * 16) * E_DIM, &Ks[wave][c * 16][0]);
    gld_lds16(gV + (size_t)(c * 16) * S_LEN, &Vs[hv][db * 64 + c * 16][0]);
  }
  __syncthreads();

  const int srow0 = q0 + wave * 32 + quad * 4;

  for (int it = 0; it < niter; ++it) {
    const int t0 = it * 64;

    // Gt loads (registers; consumed after barrier A)
    ushort4v g4[2][4];
#pragma unroll
    for (int s = 0; s < 2; ++s)
#pragma unroll
      for (int nt = 0; nt < 4; ++nt) {
        int tg = tbase + t0 + nt * 16 + l15;
        g4[s][nt] = *(const ushort4v*)(Gt + (size_t)tg * S_LEN + srow0 + s * 16);
      }

    // S' = Q K^T (exp2 domain)
    f32x4 sA[2][4];
#pragma unroll
    for (int nt = 0; nt < 4; ++nt) { sA[0][nt] = zero4; sA[1][nt] = zero4; }
#pragma unroll
    for (int nt = 0; nt < 4; ++nt)
#pragma unroll
      for (int kk = 0; kk < 4; ++kk) {
        short8 bK = *(const short8*)&Ks[kk][nt * 16 + l15][kswz];
        sA[0][nt] = __builtin_amdgcn_mfma_f32_16x16x32_bf16(aq[0][kk], bK, sA[0][nt], 0, 0, 0);
        sA[1][nt] = __builtin_amdgcn_mfma_f32_16x16x32_bf16(aq[1][kk], bK, sA[1][nt], 0, 0, 0);
      }
    __syncthreads();   // A: all waves done reading Ks; drains V(t) + Gt of this iter

    // issue K(t+1) staging (drains at barrier B, overlapped with softmax+PV)
    if (it + 1 < niter) {
#pragma unroll
      for (int c = 0; c < 4; ++c)
        gld_lds16(gK + (size_t)(t0 + 64 + c * 16) * E_DIM, &Ks[wave][c * 16][0]);
    }

    // fixed-base softmax: p = exp2(s'), masked -> 0
#pragma unroll
    for (int s = 0; s < 2; ++s)
#pragma unroll
      for (int nt = 0; nt < 4; ++nt)
#pragma unroll
        for (int r = 0; r < 4; ++r) {
          float gv = bf16_to_f32(g4[s][nt][r]);
          float x = (gv < 0.0f) ? -1e9f : sA[s][nt][r];
          float e = EXP2F(x);
          l_i[s][r] += e;
          union { float f; unsigned u; } pb; pb.f = e * gv;
          Ps[wave][(s * 16 + quad * 4 + r) * 68 + nt * 16 + l15] =
              (unsigned short)((pb.u + 0x8000u) >> 16);
        }

    // O += P V (per-wave Ps: same-wave lgkm ordering, no barrier)
    short8 ap00 = *(const short8*)&Ps[wave][l15 * 68 + quad * 8];
    short8 ap01 = *(const short8*)&Ps[wave][l15 * 68 + 32 + quad * 8];
    short8 ap10 = *(const short8*)&Ps[wave][(16 + l15) * 68 + quad * 8];
    short8 ap11 = *(const short8*)&Ps[wave][(16 + l15) * 68 + 32 + quad * 8];
#pragma unroll
    for (int dt = 0; dt < 8; ++dt) {
      short8 b0 = *(const short8*)&Vs[0][dt * 16 + l15][kswz];
      short8 b1 = *(const short8*)&Vs[1][dt * 16 + l15][kswz];
      o[0][dt] = __builtin_amdgcn_mfma_f32_16x16x32_bf16(ap00, b0, o[0][dt], 0, 0, 0);
      o[0][dt] = __builtin_amdgcn_mfma_f32_16x16x32_bf16(ap01, b1, o[0][dt], 0, 0, 0);
      o[1][dt] = __builtin_amdgcn_mfma_f32_16x16x32_bf16(ap10, b0, o[1][dt], 0, 0, 0);
      o[1][dt] = __builtin_amdgcn_mfma_f32_16x16x32_bf16(ap11, b1, o[1][dt], 0, 0, 0);
    }
    __syncthreads();   // B: all waves done reading Vs; drains own K(t+1)

    // issue V(t+1) staging (drains at barrier A of next iter, overlapped with QK)
    if (it + 1 < niter) {
#pragma unroll
      for (int c = 0; c < 4; ++c)
        gld_lds16(gV + (size_t)(c * 16) * S_LEN + t0 + 64, &Vs[hv][db * 64 + c * 16][0]);
    }
  }

  // epilogue: reduce l over the 16 lanes of each row; write partials
#pragma unroll
  for (int s = 0; s < 2; ++s)
#pragma unroll
    for (int r = 0; r < 4; ++r) {
#pragma unroll
      for (int off = 1; off < 16; off <<= 1)
        l_i[s][r] += __shfl_xor(l_i[s][r], off, 64);
    }
  if (l15 == 0) {
#pragma unroll
    for (int s = 0; s < 2; ++s)
#pragma unroll
      for (int r = 0; r < 4; ++r) {
        int gr = srow0 + s * 16 + r;
        LP[((size_t)ts * NH + h) * S_LEN + gr] = l_i[s][r];
      }
  }
  unsigned short* op = OP + (size_t)ts * S_LEN * E_DIM;
#pragma unroll
  for (int s = 0; s < 2; ++s)
#pragma unroll
    for (int dt = 0; dt < 8; ++dt)
#pragma unroll
      for (int r = 0; r < 4; ++r) {
        int gr = q0 + wave * 32 + s * 16 + quad * 4 + r;
        int gc = h * DKD + dt * 16 + l15;
        op[(size_t)gr * E_DIM + gc] = f32_to_bf16(o[s][dt][r]);
      }
}

// ---------------- combine t-split partials: Z = (O0+O1+O2)/(l0+l1+l2) ----------------
__global__ __launch_bounds__(256) void combine(const unsigned short* __restrict__ OP,
                                               const float* __restrict__ LP,
                                               unsigned short* __restrict__ Z) {
  const int s = blockIdx.x;
  const int e0 = threadIdx.x * 4;
  const int h = e0 >> 7;
  const float l = LP[(size_t)h * S_LEN + s] +
                  LP[(size_t)(NH + h) * S_LEN + s] +
                  LP[(size_t)(2 * NH + h) * S_LEN + s];
  const float inv = 1.0f / l;
  const size_t sz = (size_t)S_LEN * E_DIM;
  ushort4v a = *(const ushort4v*)(OP + (size_t)s * E_DIM + e0);
  ushort4v b = *(const ushort4v*)(OP + sz + (size_t)s * E_DIM + e0);
  ushort4v c = *(const ushort4v*)(OP + 2 * sz + (size_t)s * E_DIM + e0);
  ushort4v pk;
#pragma unroll
  for (int j = 0; j < 4; ++j)
    pk[j] = f32_to_bf16((bf16_to_f32(a[j]) + bf16_to_f32(b[j]) + bf16_to_f32(c[j])) * inv);
  *(ushort4v*)(Z + (size_t)s * E_DIM + e0) = pk;
}

// ---------------- LayerNorm ----------------
__global__ __launch_bounds__(256) void ln_fwd(const float* __restrict__ Y,
                                              const float* __restrict__ g,
                                              const float* __restrict__ b,
                                              float* __restrict__ out) {
  const int row = blockIdx.x;
  const int tid = threadIdx.x;
  const float* y = Y + (size_t)row * E_DIM;
  f32x4 v = *(const f32x4*)(y + tid * 4);
  float s = v.x + v.y + v.z + v.w;
  float s2 = v.x * v.x + v.y * v.y + v.z * v.z + v.w * v.w;
#pragma unroll
  for (int off = 32; off > 0; off >>= 1) {
    s += __shfl_down(s, off, 64);
    s2 += __shfl_down(s2, off, 64);
  }
  __shared__ float red[8];
  __shared__ float mu_s, rs_s;
  const int wave = tid >> 6, lane = tid & 63;
  if (lane == 0) { red[wave] = s; red[4 + wave] = s2; }
  __syncthreads();
  if (tid == 0) {
    float ts = red[0] + red[1] + red[2] + red[3];
    float ts2 = red[4] + red[5] + red[6] + red[7];
    float mu = ts * (1.0f / E_DIM);
    float var = ts2 * (1.0f / E_DIM) - mu * mu;
    mu_s = mu;
    rs_s = rsqrtf(var + 1e-5f);
  }
  __syncthreads();
  const float mu = mu_s, rs = rs_s;
  f32x4 gg = *(const f32x4*)(g + tid * 4);
  f32x4 bb = *(const f32x4*)(b + tid * 4);
  f32x4 ov;
  ov.x = (v.x - mu) * rs * gg.x + bb.x;
  ov.y = (v.y - mu) * rs * gg.y + bb.y;
  ov.z = (v.z - mu) * rs * gg.z + bb.z;
  ov.w = (v.w - mu) * rs * gg.w + bb.w;
  *(f32x4*)(out + (size_t)row * E_DIM + tid * 4) = ov;
}

extern "C" void kernel_launch(void* const* d_in, const int* in_sizes, int n_in,
                              void* d_out, int out_size, void* d_ws, size_t ws_size,
                              hipStream_t stream) {
  const float* q   = (const float*)d_in[0];
  const float* k   = (const float*)d_in[1];
  const float* v   = (const float*)d_in[2];
  const int*  mask = (const int*)d_in[3];
  const float* gp  = (const float*)d_in[4];
  const float* Wq  = (const float*)d_in[5];
  const float* bq  = (const float*)d_in[6];
  const float* Wk  = (const float*)d_in[7];
  const float* bk  = (const float*)d_in[8];
  const float* Wv  = (const float*)d_in[9];
  const float* bv  = (const float*)d_in[10];
  const float* Wo  = (const float*)d_in[11];
  const float* bo  = (const float*)d_in[12];
  const float* lng = (const float*)d_in[13];
  const float* lnb = (const float*)d_in[14];

  char* ws = (char*)d_ws;
  const size_t MB = 1024 * 1024;
  // layout, 88 MB peak (lifetimes disjoint where overlapped):
  unsigned short* WOB  = (unsigned short*)(ws + 0);      // Wo bf16 [0,2)
  unsigned short* WQKV = (unsigned short*)(ws + 2 * MB); // Wq,Wk,Wv [2,8) dead after proj
  float* LPb = (float*)(ws + 2 * MB);                    // [2,2.4) l-partials (after proj)
  unsigned short* XB = (unsigned short*)(ws + 8 * MB);   // q,k,v bf16 [8,32) dead after proj
  unsigned short* GT = (unsigned short*)(ws + 8 * MB);   // [8,40) built after proj
  unsigned short* QH = (unsigned short*)(ws + 40 * MB);  // [40,48) dead after attn
  unsigned short* KH = (unsigned short*)(ws + 48 * MB);  // [48,56) dead after attn
  unsigned short* VT = (unsigned short*)(ws + 56 * MB);  // [56,64) dead after attn
  unsigned short* ZB = (unsigned short*)(ws + 40 * MB);  // [40,48) written by combine
  float* YF = (float*)(ws + 48 * MB);                    // [48,64) written by out_proj
  unsigned short* OP = (unsigned short*)(ws + 64 * MB);  // [64,88) O-partials (3x8MB)

  cvt_all<<<dim3(4096, 7), 256, 0, stream>>>(q, k, v, Wq, Wk, Wv, Wo,
                                             (unsigned short*)ws);
  proj_qkv<<<dim3(32, 8, 3), 256, 0, stream>>>(XB, WQKV, bq, bk, bv, QH, KH, VT);
  build_gt<<<dim3(64, 64), 256, 0, stream>>>(mask, gp, GT);   // overwrites XB
  attn_fwd<<<dim3(32, 8, 3), 256, 0, stream>>>(QH, KH, VT, GT, OP, LPb);
  combine<<<S_LEN, 256, 0, stream>>>(OP, LPb, ZB);
  out_proj<<<dim3(32, 16), 256, 0, stream>>>(ZB, WOB, bo, q, YF);
  ln_fwd<<<S_LEN, 256, 0, stream>>>(YF, lng, lnb, (float*)d_out);
}